// Round 6
// baseline (630.059 us; speedup 1.0000x reference)
//
#include <hip/hip_runtime.h>
#include <hip/hip_bf16.h>

// Problem constants
#define CC     128        // C
#define TT     12         // T
#define NNODE  4096       // N
#define NE     266240     // E = 2*131072 + 4096
#define EHALF  131072
#define F1     512        // 4C
#define EPS    1e-5f
#define RSQRTC 0.08838834764831845f  // 1/sqrt(128)
#define EB     64         // edges per block in stats kernel
#define NBLKG  4160       // NE/EB
#define EBG    32         // edges per block in gemm kernel
#define NBLKG2 8320       // NE/EBG

// -------- workspace layout (float offsets) --------
#define O_XWM   0ull        // 524288 (zeroed)  xw_mean[N][C]
#define O_SUM1  524288ull   // 512    (zeroed)
#define O_SQ1   524800ull   // 512    (zeroed)
#define O_ICNT  525312ull   // 128    (zeroed; int at [0])
#define O_GTB   525440ull   // bf16[128*128] -> 8192 float slots  (G^T)
#define O_W0B   533632ull   // bf16[128] -> 64
#define O_WC1   533696ull   // 65536   Wv@W1a
#define O_WC2   599232ull   // 65536   Wv@W1b
#define O_B1C   664768ull   // 512
#define O_M1    665280ull   // 512
#define O_IS1   665792ull   // 512
#define O_M2    666304ull   // 128
#define O_IS2   666432ull   // 128
#define O_W2T   666560ull   // bf16[128*512] -> 32768
#define O_PB    699328ull   // bf16[4096*512] -> 1048576
#define O_QB    1747904ull  // 1048576
#define O_ALLA  2796480ull  // 266240
#define O_PART  3062720ull  // 256*8320 = 2129920
#define O_Z2    5192640ull  // bf16[NE*128] -> 17039360
// end = 22,232,000 floats ≈ 88.9 MB

typedef __attribute__((ext_vector_type(8))) short bf16x8;
typedef __attribute__((ext_vector_type(4))) float f32x4;

__device__ inline float bfbits2f(unsigned int v) { return __uint_as_float(v << 16); }
__device__ inline unsigned short f2bf(float x) {
  union { __hip_bfloat16 h; unsigned short u; } cv;
  cv.h = __float2bfloat16(x);
  return cv.u;
}
__device__ inline float f4get(const float4& v, int k) {
  return k == 0 ? v.x : k == 1 ? v.y : k == 2 ? v.z : v.w;
}

// ---------------- K0: Gtb = (Wq Wk^T)^T bf16; w0b = bf16(Wk bq) ----------------------
__global__ void k_pre(const float* __restrict__ Wq, const float* __restrict__ bq,
                      const float* __restrict__ Wk,
                      unsigned short* __restrict__ Gtb, unsigned short* __restrict__ w0b) {
  int i = blockIdx.x, j = threadIdx.x;   // G[i][j] = sum_c Wq[i][c] Wk[j][c]
  float acc = 0.f;
  for (int co = 0; co < CC; ++co) acc = fmaf(Wq[i*CC+co], Wk[j*CC+co], acc);
  Gtb[j*CC + i] = f2bf(acc);             // transposed store: Gtb[c'][c] = G[c][c']
  if (j == 0) {
    float a = 0.f;
    for (int co = 0; co < CC; ++co) a = fmaf(Wk[i*CC+co], bq[co], a);
    w0b[i] = f2bf(a);
  }
}

// ---------------- K0b: Wc1 = Wv@W1a, Wc2 = Wv@W1b, b1c = b1 + 12 bv@(W1a+W1b) --------
__global__ __launch_bounds__(256) void k_prew(const float* __restrict__ Wv,
    const float* __restrict__ bv, const float* __restrict__ W1, const float* __restrict__ b1,
    float* __restrict__ Wc1, float* __restrict__ Wc2, float* __restrict__ b1c) {
  __shared__ float wvr[CC];
  const int c = blockIdx.x, tid = threadIdx.x;
  if (tid < CC) wvr[tid] = Wv[(size_t)c*CC + tid];
  __syncthreads();
  for (int h = 0; h < 2; ++h) {
    int f = h*256 + tid;
    float a1 = 0.f, a2 = 0.f;
    for (int j = 0; j < CC; ++j) {
      float wv = wvr[j];
      a1 = fmaf(wv, W1[(size_t)j*F1 + f], a1);
      a2 = fmaf(wv, W1[(size_t)(CC + j)*F1 + f], a2);
    }
    Wc1[(size_t)c*F1 + f] = a1;
    Wc2[(size_t)c*F1 + f] = a2;
  }
  if (c == 0) {
    for (int h = 0; h < 2; ++h) {
      int f = h*256 + tid;
      float s = b1[f];
      for (int j = 0; j < CC; ++j)
        s = fmaf(12.f*bv[j], W1[(size_t)j*F1 + f] + W1[(size_t)(CC + j)*F1 + f], s);
      b1c[f] = s;
    }
  }
}

// ---------------- K0c: W2T bf16 [128 n][512 k] = bf16(W2[k][n]) ----------------------
__global__ void k_w2t(const float* __restrict__ W2, unsigned short* __restrict__ W2T) {
  int n = blockIdx.x;
  for (int k = threadIdx.x; k < F1; k += 256)
    W2T[(size_t)n*F1 + k] = f2bf(W2[(size_t)k*CC + n]);
}

// ---------------- K1: temporal attention -> xw_mean[N][C] (MFMA) ---------------------
// block = 8 nodes of one batch b; 4 waves. XCD-chunked swizzle: XCD k owns batch k.
__global__ __launch_bounds__(256) void k_attn(
    const float* __restrict__ h_in,
    const unsigned short* __restrict__ Gtb,
    const unsigned short* __restrict__ w0b,
    float* __restrict__ xwm) {
  __shared__ unsigned short xs[12800];  // 100 rows x 128 bf16 (256B rows, XOR swizzled)
  __shared__ unsigned short ys[12800];
  __shared__ float dsv[104];            // d[(n,t)] = x . w0
  const int tid = threadIdx.x;
  const int bid = ((blockIdx.x & 7) << 9) | (blockIdx.x >> 3);  // bijective, 4096%8==0
  const int b  = bid >> 9;
  const int n0 = (bid & 511) << 3;

  // ---- load x tile [8 n][12 t][128 c] -> xs bf16, row = n_loc*12+t, swizzled ----
  {
    const float* hb = h_in + ((size_t)b*CC*TT)*NNODE + n0;
    #pragma unroll
    for (int it = 0; it < 3; ++it) {
      int p = it*256 + tid;          // [0,768): c-pair x t
      int c2 = p & 63;               // c = 2*c2, 2*c2+1
      int t  = p >> 6;               // 0..11
      const float* g0 = hb + ((size_t)(2*c2)*TT + t)*NNODE;
      const float* g1 = g0 + (size_t)(TT*NNODE);
      float4 a0 = *(const float4*)g0;
      float4 a1 = *(const float4*)(g0 + 4);
      float4 b0 = *(const float4*)g1;
      float4 b1 = *(const float4*)(g1 + 4);
      #pragma unroll
      for (int i = 0; i < 8; ++i) {
        float va = (i < 4) ? f4get(a0, i) : f4get(a1, i - 4);
        float vb = (i < 4) ? f4get(b0, i) : f4get(b1, i - 4);
        int r = i*TT + t;
        unsigned byte = ((unsigned)r << 8) + (((unsigned)(c2*4)) ^ (((unsigned)(r & 7)) << 4));
        *(unsigned*)((char*)xs + byte) = (unsigned)f2bf(va) | ((unsigned)f2bf(vb) << 16);
      }
    }
  }

  const int w = tid >> 6, lane = tid & 63;
  const int l15 = lane & 15, l4 = lane >> 4;

  // ---- preload G^T A-fragments (wave owns c' rows w*32..w*32+31) ----
  bf16x8 gfr[2][4];
  #pragma unroll
  for (int mt = 0; mt < 2; ++mt)
    #pragma unroll
    for (int kt = 0; kt < 4; ++kt)
      gfr[mt][kt] = *(const bf16x8*)(Gtb + (size_t)((w<<5) + (mt<<4) + l15)*CC + (kt<<5) + (l4<<3));
  bf16x8 wfr[4];
  if (w == 3) {
    #pragma unroll
    for (int kt = 0; kt < 4; ++kt) {
      bf16x8 z = {0,0,0,0,0,0,0,0};
      if (l15 == 0) z = *(const bf16x8*)(w0b + (kt<<5) + (l4<<3));
      wfr[kt] = z;
    }
  }
  __syncthreads();

  // ---- Y^T = G^T @ X^T  (M = c' = 128 split across waves; N = 96 (n,t) cols) ----
  #pragma unroll
  for (int np = 0; np < 2; ++np) {
    f32x4 acc[2][3];
    f32x4 accd[3];
    #pragma unroll
    for (int mt = 0; mt < 2; ++mt)
      #pragma unroll
      for (int nt = 0; nt < 3; ++nt) acc[mt][nt] = (f32x4){0.f,0.f,0.f,0.f};
    #pragma unroll
    for (int nt = 0; nt < 3; ++nt) accd[nt] = (f32x4){0.f,0.f,0.f,0.f};

    #pragma unroll
    for (int kt = 0; kt < 4; ++kt) {
      bf16x8 bfr[3];
      #pragma unroll
      for (int nt = 0; nt < 3; ++nt) {
        int rr = np*48 + nt*16 + l15;
        unsigned byte = ((unsigned)rr << 8) +
                        (((unsigned)((kt<<6) + (l4<<4))) ^ (((unsigned)(rr & 7)) << 4));
        bfr[nt] = *(const bf16x8*)((const char*)xs + byte);
      }
      #pragma unroll
      for (int mt = 0; mt < 2; ++mt)
        #pragma unroll
        for (int nt = 0; nt < 3; ++nt)
          acc[mt][nt] = __builtin_amdgcn_mfma_f32_16x16x32_bf16(gfr[mt][kt], bfr[nt], acc[mt][nt], 0, 0, 0);
      if (w == 3) {
        #pragma unroll
        for (int nt = 0; nt < 3; ++nt)
          accd[nt] = __builtin_amdgcn_mfma_f32_16x16x32_bf16(wfr[kt], bfr[nt], accd[nt], 0, 0, 0);
      }
    }
    // write y fragments: lane col=(n,t)=rr, rows c' = w*32+mt*16+l4*4+reg (4 consec) -> b64
    #pragma unroll
    for (int mt = 0; mt < 2; ++mt)
      #pragma unroll
      for (int nt = 0; nt < 3; ++nt) {
        int rr = np*48 + nt*16 + l15;
        ushort4 v;
        v.x = f2bf(acc[mt][nt][0]); v.y = f2bf(acc[mt][nt][1]);
        v.z = f2bf(acc[mt][nt][2]); v.w = f2bf(acc[mt][nt][3]);
        unsigned cb = (unsigned)((w<<6) + (mt<<5) + (l4<<3));
        unsigned byte = ((unsigned)rr << 8) + (cb ^ (((unsigned)(rr & 7)) << 4));
        *(ushort4*)((char*)ys + byte) = v;
      }
    if (w == 3 && l4 == 0) {
      #pragma unroll
      for (int nt = 0; nt < 3; ++nt)
        dsv[np*48 + nt*16 + l15] = accd[nt][0];   // row 0 of the w0-Mt = d
    }
  }
  __syncthreads();

  // ---- per-node scores MFMA + softmax + xw (wave handles nodes 2w, 2w+1) ----
  #pragma unroll
  for (int nn = 0; nn < 2; ++nn) {
    const int n = (w << 1) + nn;
    const int rb = n*TT;
    const int rr = rb + l15;
    f32x4 sa = (f32x4){0.f,0.f,0.f,0.f};
    #pragma unroll
    for (int kt = 0; kt < 4; ++kt) {
      unsigned byte = ((unsigned)rr << 8) +
                      (((unsigned)((kt<<6) + (l4<<4))) ^ (((unsigned)(rr & 7)) << 4));
      bf16x8 afr = *(const bf16x8*)((const char*)ys + byte);  // y rows t
      bf16x8 bfr = *(const bf16x8*)((const char*)xs + byte);  // x rows s (as B)
      sa = __builtin_amdgcn_mfma_f32_16x16x32_bf16(afr, bfr, sa, 0, 0, 0);
    }
    // S[t = l4*4+reg][s = l15]; add d[s], scale, softmax over s (row-wise)
    float dv = dsv[rr];
    const bool sval = (l15 < TT);
    float p[4];
    #pragma unroll
    for (int r = 0; r < 4; ++r) {
      float t1 = sval ? (sa[r] + dv) * RSQRTC : -1e30f;
      float m = t1;
      m = fmaxf(m, __shfl_xor(m, 1));
      m = fmaxf(m, __shfl_xor(m, 2));
      m = fmaxf(m, __shfl_xor(m, 4));
      m = fmaxf(m, __shfl_xor(m, 8));
      float e = exp2f((t1 - m) * 1.4426950408889634f);
      float s = e;
      s += __shfl_xor(s, 1);
      s += __shfl_xor(s, 2);
      s += __shfl_xor(s, 4);
      s += __shfl_xor(s, 8);
      p[r] = e / s;
    }
    // w[s] = sum_t P[t][s]; rows t=12..15 live entirely in l4==3 -> mask
    float wpart = (l4 < 3) ? (p[0] + p[1] + p[2] + p[3]) : 0.f;
    wpart += __shfl_xor(wpart, 16);
    wpart += __shfl_xor(wpart, 32);
    // xw[c] = sum_s w[s] x[n,s,c]; lane owns c = 2*lane, 2*lane+1
    float xw0 = 0.f, xw1 = 0.f;
    #pragma unroll
    for (int s = 0; s < TT; ++s) {
      float wv = __shfl(wpart, s);       // lane s holds w[s]
      int r2 = rb + s;
      unsigned byte = ((unsigned)r2 << 8) +
                      (((unsigned)(lane << 2)) ^ (((unsigned)(r2 & 7)) << 4));
      unsigned xp = *(const unsigned*)((const char*)xs + byte);
      xw0 = fmaf(wv, bfbits2f(xp & 0xffffu), xw0);
      xw1 = fmaf(wv, bfbits2f(xp >> 16), xw1);
    }
    unsafeAtomicAdd(&xwm[(size_t)(n0 + n)*CC + (lane << 1)],     xw0 * 0.125f);
    unsafeAtomicAdd(&xwm[(size_t)(n0 + n)*CC + (lane << 1) + 1], xw1 * 0.125f);
  }
}

// ---------------- K2: P = xwm@Wc1 + b1c, Q = xwm@Wc2 (bf16 out) ----------------------
__global__ __launch_bounds__(256) void k_pq(const float* __restrict__ xwm,
    const float* __restrict__ Wc1, const float* __restrict__ Wc2,
    const float* __restrict__ b1c,
    unsigned short* __restrict__ Pb, unsigned short* __restrict__ Qb) {
  __shared__ float em[4][CC];
  const int tid = threadIdx.x;
  const int n0 = blockIdx.x << 2;
  for (int i = tid; i < 4*CC; i += 256)
    em[i >> 7][i & 127] = xwm[(size_t)(n0 + (i >> 7))*CC + (i & 127)];
  __syncthreads();
  for (int nn = 0; nn < 4; ++nn) {
    for (int half = 0; half < 2; ++half) {
      int f = half*256 + tid;
      float ap = b1c[f], aq = 0.f;
      for (int c = 0; c < CC; ++c) {
        float e = em[nn][c];
        ap = fmaf(e, Wc1[(size_t)c*F1 + f], ap);
        aq = fmaf(e, Wc2[(size_t)c*F1 + f], aq);
      }
      Pb[(size_t)(n0+nn)*F1 + f] = f2bf(ap);
      Qb[(size_t)(n0+nn)*F1 + f] = f2bf(aq);
    }
  }
}

// ---------------- K3: masked stats of z1 = P[row]+Q[col] (batched uint4 gathers) -----
__global__ __launch_bounds__(256) void k_stats1(const unsigned short* __restrict__ Pb,
    const unsigned short* __restrict__ Qb, const int* __restrict__ row,
    const int* __restrict__ col,
    float* __restrict__ sum1, float* __restrict__ sq1, int* __restrict__ icnt) {
  __shared__ int rS[EB], cS[EB]; __shared__ float mk[EB];
  __shared__ float sred[F1], qred[F1];
  const int tid = threadIdx.x;
  const int e0 = blockIdx.x * EB;
  if (tid < EB) {
    int r = row[e0+tid], c = col[e0+tid];
    rS[tid] = r; cS[tid] = c; mk[tid] = (r != c) ? 1.f : 0.f;
  }
  sred[tid] = 0.f; sred[tid+256] = 0.f;
  qred[tid] = 0.f; qred[tid+256] = 0.f;
  __syncthreads();
  if (tid == 0) {
    int lc = 0;
    for (int j = 0; j < EB; ++j) lc += (rS[j] != cS[j]);
    atomicAdd(icnt, lc);
  }
  const int fg = (tid & 63) << 3;   // 8 features per thread
  const int jg = (tid >> 6) << 4;   // wave's first edge
  float s[8], q[8];
  #pragma unroll
  for (int u = 0; u < 8; ++u) { s[u] = 0.f; q[u] = 0.f; }
  #pragma unroll
  for (int i0 = 0; i0 < 16; i0 += 4) {
    // prefetch 4 edges' indices, then issue all 8 gathers back-to-back
    int rr[4], cc[4]; float mm[4];
    #pragma unroll
    for (int u = 0; u < 4; ++u) {
      int j = jg + i0 + u;
      rr[u] = rS[j]; cc[u] = cS[j]; mm[u] = mk[j];
    }
    uint4 pv[4], qv[4];
    #pragma unroll
    for (int u = 0; u < 4; ++u) pv[u] = *(const uint4*)(Pb + (size_t)rr[u]*F1 + fg);
    #pragma unroll
    for (int u = 0; u < 4; ++u) qv[u] = *(const uint4*)(Qb + (size_t)cc[u]*F1 + fg);
    #pragma unroll
    for (int u = 0; u < 4; ++u) {
      float m = mm[u];
      #pragma unroll
      for (int k = 0; k < 4; ++k) {
        unsigned pu = (&pv[u].x)[k], qu = (&qv[u].x)[k];
        float za = bfbits2f(pu & 0xffffu) + bfbits2f(qu & 0xffffu);
        float zb = bfbits2f(pu >> 16)     + bfbits2f(qu >> 16);
        s[2*k]   = fmaf(m, za, s[2*k]);   q[2*k]   = fmaf(m*za, za, q[2*k]);
        s[2*k+1] = fmaf(m, zb, s[2*k+1]); q[2*k+1] = fmaf(m*zb, zb, q[2*k+1]);
      }
    }
  }
  #pragma unroll
  for (int u = 0; u < 8; ++u) {
    atomicAdd(&sred[fg+u], s[u]);
    atomicAdd(&qred[fg+u], q[u]);
  }
  __syncthreads();
  unsafeAtomicAdd(&sum1[tid],     sred[tid]);
  unsafeAtomicAdd(&sum1[tid+256], sred[tid+256]);
  unsafeAtomicAdd(&sq1[tid],      qred[tid]);
  unsafeAtomicAdd(&sq1[tid+256],  qred[tid+256]);
}

__global__ void k_fin1(const float* __restrict__ sum1, const float* __restrict__ sq1,
                       const int* __restrict__ icnt, float* __restrict__ m1,
                       float* __restrict__ is1) {
  int f = threadIdx.x;
  float cnt = (float)(*icnt);
  float m = sum1[f] / cnt;
  m1[f] = m;
  is1[f] = rsqrtf(sq1[f]/cnt - m*m + EPS);
}

// ---------------- K4: h1 = relu(IN(z1)) -> bf16 LDS (swizzled); z2 = h1@W2 via MFMA --
// EBG=32 edges/block, ~38 KB LDS -> 4 blocks/CU (16 waves/CU) for latency hiding.
__global__ __launch_bounds__(256, 4) void k_gemm(const unsigned short* __restrict__ Pb,
    const unsigned short* __restrict__ Qb, const int* __restrict__ row,
    const int* __restrict__ col,
    const float* __restrict__ m1, const float* __restrict__ is1,
    const unsigned short* __restrict__ W2T, const float* __restrict__ b2,
    unsigned short* __restrict__ z2, float* __restrict__ part) {
  __shared__ unsigned short h1s[EBG*F1];  // 32 KB, XOR-swizzled rows; reused as f32 staging
  __shared__ float m1s[F1], is1s[F1];
  __shared__ int rS[EBG], cS[EBG]; __shared__ float mk[EBG];
  __shared__ float cstat[256];
  const int tid = threadIdx.x;
  const int bid = blockIdx.x;
  const int e0 = bid * EBG;
  const int w = tid >> 6, lane = tid & 63;
  const int wn0 = w << 5;
  const int l15 = lane & 15, l4 = lane >> 4;
  if (tid < EBG) {
    int r = row[e0+tid], c = col[e0+tid];
    rS[tid] = r; cS[tid] = c; mk[tid] = (r != c) ? 1.f : 0.f;
  }
  cstat[tid] = 0.f;
  for (int i = tid; i < F1; i += 256) { m1s[i] = m1[i]; is1s[i] = is1[i]; }
  __syncthreads();

  // ---- stage h1 (bf16, swizzled): row j = tid>>3, 8 chunks of 16B; 4-batched loads --
  {
    const int j = tid >> 3;
    const unsigned short* pr = Pb + (size_t)rS[j]*F1;
    const unsigned short* qr = Qb + (size_t)cS[j]*F1;
    const int sw = (j & 7) << 4;
    const unsigned rowb = (unsigned)j << 10;
    const float* m1p = &m1s[0];
    const float* is1p = &is1s[0];
    #pragma unroll
    for (int half = 0; half < 2; ++half) {
      uint4 pv[4], qv[4];
      #pragma unroll
      for (int u = 0; u < 4; ++u) {
        int k0 = (((tid & 7) + ((half*4 + u) << 3)) << 3);
        pv[u] = *(const uint4*)(pr + k0);
        qv[u] = *(const uint4*)(qr + k0);
      }
      #pragma unroll
      for (int u = 0; u < 4; ++u) {
        int k0 = (((tid & 7) + ((half*4 + u) << 3)) << 3);
        unsigned out[4];
        #pragma unroll
        for (int q = 0; q < 4; ++q) {
          unsigned pu = (&pv[u].x)[q], qu = (&qv[u].x)[q];
          int k = k0 + 2*q;
          float2 mm = *(const float2*)&m1p[k];
          float2 ii = *(const float2*)&is1p[k];
          float za = bfbits2f(pu & 0xffffu) + bfbits2f(qu & 0xffffu);
          float zb = bfbits2f(pu >> 16)     + bfbits2f(qu >> 16);
          float ha = fmaxf((za - mm.x)*ii.x, 0.f);
          float hb = fmaxf((zb - mm.y)*ii.y, 0.f);
          out[q] = (unsigned)f2bf(ha) | ((unsigned)f2bf(hb) << 16);
        }
        unsigned byte = rowb + (((unsigned)(k0 << 1)) ^ sw);
        *(uint4*)((char*)h1s + byte) = make_uint4(out[0], out[1], out[2], out[3]);
      }
    }
  }

  // ---- preload ALL W2T B-fragments into registers (in flight across barrier) ----
  bf16x8 bfr[16][2];
  #pragma unroll
  for (int kt = 0; kt < 16; ++kt)
    #pragma unroll
    for (int nt = 0; nt < 2; ++nt)
      bfr[kt][nt] = *(const bf16x8*)(W2T + (size_t)(wn0 + (nt << 4) + l15)*F1 + (kt << 5) + (l4 << 3));
  __syncthreads();

  // ---- MFMA: 32x128 = [32xK] @ W2T^T, K=512; loop is pure ds_read + MFMA ----
  f32x4 acc[2][2];
  #pragma unroll
  for (int a = 0; a < 2; ++a)
    #pragma unroll
    for (int c = 0; c < 2; ++c) acc[a][c] = (f32x4){0.f,0.f,0.f,0.f};

  #pragma unroll
  for (int kt = 0; kt < 16; ++kt) {
    bf16x8 afr[2];
    #pragma unroll
    for (int mt = 0; mt < 2; ++mt) {
      int j = (mt << 4) + l15;
      unsigned byte = ((unsigned)j << 10) + (((unsigned)(kt*64 + l4*16)) ^ ((j & 7) << 4));
      afr[mt] = *(const bf16x8*)((const char*)h1s + byte);
    }
    #pragma unroll
    for (int mt = 0; mt < 2; ++mt)
      #pragma unroll
      for (int nt = 0; nt < 2; ++nt)
        acc[mt][nt] = __builtin_amdgcn_mfma_f32_16x16x32_bf16(afr[mt], bfr[kt][nt], acc[mt][nt], 0, 0, 0);
  }
  __syncthreads();   // all h1s reads done; safe to reuse as f32 staging

  // ---- epilogue: +b2, masked col stats, z -> LDS f32 [32][132] ----
  float* z2s = (float*)&h1s[0];
  float sloc[2] = {0.f, 0.f}, qloc[2] = {0.f, 0.f};
  #pragma unroll
  for (int nt = 0; nt < 2; ++nt) {
    int colg = wn0 + (nt << 4) + l15;
    float bb = b2[colg];
    #pragma unroll
    for (int mt = 0; mt < 2; ++mt) {
      f32x4 v = acc[mt][nt];
      #pragma unroll
      for (int reg = 0; reg < 4; ++reg) {
        int j = (mt << 4) + (l4 << 2) + reg;
        float z = v[reg] + bb;
        float m = mk[j];
        sloc[nt] = fmaf(m, z, sloc[nt]);
        qloc[nt] = fmaf(m*z, z, qloc[nt]);
        z2s[j*132 + colg] = z;
      }
    }
  }
  #pragma unroll
  for (int nt = 0; nt < 2; ++nt) {
    int colg = wn0 + (nt << 4) + l15;
    atomicAdd(&cstat[colg], sloc[nt]);
    atomicAdd(&cstat[128 + colg], qloc[nt]);
  }
  __syncthreads();

  // ---- coalesced bf16 z2 store: 2 passes x (256 threads x 8 floats) ----
  #pragma unroll
  for (int p = 0; p < 2; ++p) {
    int idx = (p << 11) + (tid << 3);       // [0, 4096)
    int j = idx >> 7, c = idx & 127;
    const float* src = &z2s[j*132 + c];
    float4 v0 = *(const float4*)src;
    float4 v1 = *(const float4*)(src + 4);
    uint4 o;
    o.x = (unsigned)f2bf(v0.x) | ((unsigned)f2bf(v0.y) << 16);
    o.y = (unsigned)f2bf(v0.z) | ((unsigned)f2bf(v0.w) << 16);
    o.z = (unsigned)f2bf(v1.x) | ((unsigned)f2bf(v1.y) << 16);
    o.w = (unsigned)f2bf(v1.z) | ((unsigned)f2bf(v1.w) << 16);
    *(uint4*)(z2 + (size_t)e0*CC + idx) = o;
  }
  if (tid < 128) {
    part[(size_t)tid*NBLKG2 + bid]         = cstat[tid];
    part[(size_t)(128 + tid)*NBLKG2 + bid] = cstat[128 + tid];
  }
}

__global__ __launch_bounds__(256) void k_fin2(const float* __restrict__ part,
    const int* __restrict__ icnt, float* __restrict__ m2, float* __restrict__ is2) {
  __shared__ float rs[256], rq[256];
  const int c = blockIdx.x, tid = threadIdx.x;
  float s = 0.f, q = 0.f;
  for (int i = tid; i < NBLKG2; i += 256) {
    s += part[(size_t)c*NBLKG2 + i];
    q += part[(size_t)(128 + c)*NBLKG2 + i];
  }
  rs[tid] = s; rq[tid] = q; __syncthreads();
  for (int st = 128; st > 0; st >>= 1) {
    if (tid < st) { rs[tid] += rs[tid+st]; rq[tid] += rq[tid+st]; }
    __syncthreads();
  }
  if (tid == 0) {
    float cnt = (float)(*icnt);
    float m = rs[0] / cnt;
    m2[c] = m;
    is2[c] = rsqrtf(rq[0]/cnt - m*m + EPS);
  }
}

// ---------------- K5a: logits -> att (no table; att is a function of (r,c)) ---------
__global__ __launch_bounds__(256) void k_score(const unsigned short* __restrict__ z2,
    const int* __restrict__ row, const int* __restrict__ col,
    const float* __restrict__ m2, const float* __restrict__ is2,
    const float* __restrict__ W3, const float* __restrict__ b3,
    float* __restrict__ all_att) {
  __shared__ float zt[64][129];
  const int tid = threadIdx.x;
  const int e0 = blockIdx.x << 6;
  const uint4* src = reinterpret_cast<const uint4*>(z2 + (size_t)e0*CC);
  for (int i = tid; i < 64*CC/8; i += 256) {
    uint4 v = src[i];
    int flat = i*8;
    int j = flat >> 7, k = flat & 127;
    zt[j][k+0] = bfbits2f(v.x & 0xffffu); zt[j][k+1] = bfbits2f(v.x >> 16);
    zt[j][k+2] = bfbits2f(v.y & 0xffffu); zt[j][k+3] = bfbits2f(v.y >> 16);
    zt[j][k+4] = bfbits2f(v.z & 0xffffu); zt[j][k+5] = bfbits2f(v.z >> 16);
    zt[j][k+6] = bfbits2f(v.w & 0xffffu); zt[j][k+7] = bfbits2f(v.w >> 16);
  }
  __syncthreads();
  const int j = tid >> 2, q = tid & 3;
  float a = 0.f;
  for (int k = q*32; k < q*32 + 32; ++k)
    a = fmaf(fmaxf((zt[j][k] - m2[k])*is2[k], 0.f), W3[k], a);
  a += __shfl_xor(a, 1, 4);
  a += __shfl_xor(a, 2, 4);
  if (q == 0) {
    int e = e0 + j;
    int r = row[e], c = col[e];
    float att;
    if (r == c) att = 1.f;
    else        att = 1.f / (1.f + expf(-(a + b3[0])));
    all_att[e] = att;
  }
}

// ---------------- K5b: out = 0.5*(att + att[analytic reverse partner]) ---------------
__global__ __launch_bounds__(256) void k_out(const float* __restrict__ all_att,
    float* __restrict__ out) {
  int e = blockIdx.x*256 + threadIdx.x;
  int p = (e < EHALF) ? (e + EHALF) : (e < 2*EHALF ? e - EHALF : e);
  out[e] = 0.5f * (all_att[e] + all_att[p]);
}

extern "C" void kernel_launch(void* const* d_in, const int* in_sizes, int n_in,
                              void* d_out, int out_size, void* d_ws, size_t ws_size,
                              hipStream_t stream) {
  const float* h_in = (const float*)d_in[0];
  const int*   ei   = (const int*)d_in[1];
  const float* Wq = (const float*)d_in[2];
  const float* bq = (const float*)d_in[3];
  const float* Wk = (const float*)d_in[4];
  const float* bk = (const float*)d_in[5];  (void)bk;
  const float* Wv = (const float*)d_in[6];
  const float* bv = (const float*)d_in[7];
  const float* W1 = (const float*)d_in[8];
  const float* b1 = (const float*)d_in[9];
  const float* W2 = (const float*)d_in[10];
  const float* b2 = (const float*)d_in[11];
  const float* W3 = (const float*)d_in[12];
  const float* b3 = (const float*)d_in[13];
  float* ws = (float*)d_ws;
  float* out = (float*)d_out;
  const int* row = ei;
  const int* col = ei + NE;

  // zero accumulators (xwm, sum1, sq1, icnt)
  hipMemsetAsync(ws, 0, 525440ull * 4ull, stream);

  k_pre<<<128, 128, 0, stream>>>(Wq, bq, Wk,
                                 (unsigned short*)(ws+O_GTB), (unsigned short*)(ws+O_W0B));
  k_prew<<<128, 256, 0, stream>>>(Wv, bv, W1, b1, ws+O_WC1, ws+O_WC2, ws+O_B1C);
  k_w2t<<<128, 256, 0, stream>>>(W2, (unsigned short*)(ws+O_W2T));
  k_attn<<<4096, 256, 0, stream>>>(h_in, (const unsigned short*)(ws+O_GTB),
                                   (const unsigned short*)(ws+O_W0B), ws+O_XWM);
  k_pq<<<1024, 256, 0, stream>>>(ws+O_XWM, ws+O_WC1, ws+O_WC2, ws+O_B1C,
                                 (unsigned short*)(ws+O_PB), (unsigned short*)(ws+O_QB));
  k_stats1<<<NBLKG, 256, 0, stream>>>((const unsigned short*)(ws+O_PB),
                                      (const unsigned short*)(ws+O_QB), row, col,
                                      ws+O_SUM1, ws+O_SQ1, (int*)(ws+O_ICNT));
  k_fin1<<<1, 512, 0, stream>>>(ws+O_SUM1, ws+O_SQ1, (const int*)(ws+O_ICNT),
                                ws+O_M1, ws+O_IS1);
  k_gemm<<<NBLKG2, 256, 0, stream>>>((const unsigned short*)(ws+O_PB),
                                     (const unsigned short*)(ws+O_QB), row, col,
                                     ws+O_M1, ws+O_IS1,
                                     (const unsigned short*)(ws+O_W2T), b2,
                                     (unsigned short*)(ws+O_Z2), ws+O_PART);
  k_fin2<<<128, 256, 0, stream>>>(ws+O_PART, (const int*)(ws+O_ICNT), ws+O_M2, ws+O_IS2);
  k_score<<<4160, 256, 0, stream>>>((const unsigned short*)(ws+O_Z2), row, col,
                                    ws+O_M2, ws+O_IS2, W3, b3, ws+O_ALLA);
  k_out<<<1040, 256, 0, stream>>>(ws+O_ALLA, out);
}

// Round 7
// 595.801 us; speedup vs baseline: 1.0575x; 1.0575x over previous
//
#include <hip/hip_runtime.h>
#include <hip/hip_bf16.h>

// Problem constants
#define CC     128        // C
#define TT     12         // T
#define NNODE  4096       // N
#define NE     266240     // E = 2*131072 + 4096
#define EHALF  131072
#define F1     512        // 4C
#define EPS    1e-5f
#define RSQRTC 0.08838834764831845f  // 1/sqrt(128)
#define EB     64         // edges per block in stats kernel
#define NBLKG  4160       // NE/EB
#define EBG    32         // edges per block in gemm kernel
#define NBLKG2 8320       // NE/EBG

// -------- workspace layout (float offsets) --------
#define O_XWM   0ull        // 524288 (zeroed)  xw_mean[N][C]
#define O_SUM1  524288ull   // 512    (zeroed)
#define O_SQ1   524800ull   // 512    (zeroed)
#define O_ICNT  525312ull   // 128    (zeroed; int at [0])
#define O_GTB   525440ull   // bf16[128*128] -> 8192 float slots  (G^T)
#define O_W0B   533632ull   // bf16[128] -> 64
#define O_WC1   533696ull   // 65536   Wv@W1a
#define O_WC2   599232ull   // 65536   Wv@W1b
#define O_B1C   664768ull   // 512
#define O_M1    665280ull   // 512
#define O_IS1   665792ull   // 512
#define O_M2    666304ull   // 128
#define O_IS2   666432ull   // 128
#define O_W2T   666560ull   // bf16[128*512] -> 32768
#define O_PB    699328ull   // bf16[4096*512] -> 1048576
#define O_QB    1747904ull  // 1048576
#define O_ALLA  2796480ull  // 266240
#define O_PART  3062720ull  // 256*8320 = 2129920
#define O_Z2    5192640ull  // bf16[NE*128] -> 17039360
// end = 22,232,000 floats ≈ 88.9 MB

typedef __attribute__((ext_vector_type(8))) short bf16x8;
typedef __attribute__((ext_vector_type(4))) float f32x4;

__device__ inline float bfbits2f(unsigned int v) { return __uint_as_float(v << 16); }
__device__ inline unsigned short f2bf(float x) {
  union { __hip_bfloat16 h; unsigned short u; } cv;
  cv.h = __float2bfloat16(x);
  return cv.u;
}
__device__ inline float f4get(const float4& v, int k) {
  return k == 0 ? v.x : k == 1 ? v.y : k == 2 ? v.z : v.w;
}

// ---------------- K0: Gtb = (Wq Wk^T)^T bf16; w0b = bf16(Wk bq) ----------------------
__global__ void k_pre(const float* __restrict__ Wq, const float* __restrict__ bq,
                      const float* __restrict__ Wk,
                      unsigned short* __restrict__ Gtb, unsigned short* __restrict__ w0b) {
  int i = blockIdx.x, j = threadIdx.x;   // G[i][j] = sum_c Wq[i][c] Wk[j][c]
  float acc = 0.f;
  for (int co = 0; co < CC; ++co) acc = fmaf(Wq[i*CC+co], Wk[j*CC+co], acc);
  Gtb[j*CC + i] = f2bf(acc);             // transposed store: Gtb[c'][c] = G[c][c']
  if (j == 0) {
    float a = 0.f;
    for (int co = 0; co < CC; ++co) a = fmaf(Wk[i*CC+co], bq[co], a);
    w0b[i] = f2bf(a);
  }
}

// ---------------- K0b: Wc1 = Wv@W1a, Wc2 = Wv@W1b, b1c = b1 + 12 bv@(W1a+W1b) --------
__global__ __launch_bounds__(256) void k_prew(const float* __restrict__ Wv,
    const float* __restrict__ bv, const float* __restrict__ W1, const float* __restrict__ b1,
    float* __restrict__ Wc1, float* __restrict__ Wc2, float* __restrict__ b1c) {
  __shared__ float wvr[CC];
  const int c = blockIdx.x, tid = threadIdx.x;
  if (tid < CC) wvr[tid] = Wv[(size_t)c*CC + tid];
  __syncthreads();
  for (int h = 0; h < 2; ++h) {
    int f = h*256 + tid;
    float a1 = 0.f, a2 = 0.f;
    for (int j = 0; j < CC; ++j) {
      float wv = wvr[j];
      a1 = fmaf(wv, W1[(size_t)j*F1 + f], a1);
      a2 = fmaf(wv, W1[(size_t)(CC + j)*F1 + f], a2);
    }
    Wc1[(size_t)c*F1 + f] = a1;
    Wc2[(size_t)c*F1 + f] = a2;
  }
  if (c == 0) {
    for (int h = 0; h < 2; ++h) {
      int f = h*256 + tid;
      float s = b1[f];
      for (int j = 0; j < CC; ++j)
        s = fmaf(12.f*bv[j], W1[(size_t)j*F1 + f] + W1[(size_t)(CC + j)*F1 + f], s);
      b1c[f] = s;
    }
  }
}

// ---------------- K0c: W2T bf16 [128 n][512 k] = bf16(W2[k][n]) ----------------------
__global__ void k_w2t(const float* __restrict__ W2, unsigned short* __restrict__ W2T) {
  int n = blockIdx.x;
  for (int k = threadIdx.x; k < F1; k += 256)
    W2T[(size_t)n*F1 + k] = f2bf(W2[(size_t)k*CC + n]);
}

// ---------------- K1: temporal attention -> xw_mean[N][C] (MFMA) ---------------------
// block = 8 nodes of one batch b; 4 waves. XCD-chunked swizzle: XCD k owns batch k.
__global__ __launch_bounds__(256) void k_attn(
    const float* __restrict__ h_in,
    const unsigned short* __restrict__ Gtb,
    const unsigned short* __restrict__ w0b,
    float* __restrict__ xwm) {
  __shared__ unsigned short xs[12800];  // 100 rows x 128 bf16 (256B rows, XOR swizzled)
  __shared__ unsigned short ys[12800];
  __shared__ float dsv[104];            // d[(n,t)] = x . w0
  const int tid = threadIdx.x;
  const int bid = ((blockIdx.x & 7) << 9) | (blockIdx.x >> 3);  // bijective, 4096%8==0
  const int b  = bid >> 9;
  const int n0 = (bid & 511) << 3;

  // ---- load x tile [8 n][12 t][128 c] -> xs bf16, row = n_loc*12+t, swizzled ----
  {
    const float* hb = h_in + ((size_t)b*CC*TT)*NNODE + n0;
    #pragma unroll
    for (int it = 0; it < 3; ++it) {
      int p = it*256 + tid;          // [0,768): c-pair x t
      int c2 = p & 63;               // c = 2*c2, 2*c2+1
      int t  = p >> 6;               // 0..11
      const float* g0 = hb + ((size_t)(2*c2)*TT + t)*NNODE;
      const float* g1 = g0 + (size_t)(TT*NNODE);
      float4 a0 = *(const float4*)g0;
      float4 a1 = *(const float4*)(g0 + 4);
      float4 b0 = *(const float4*)g1;
      float4 b1 = *(const float4*)(g1 + 4);
      #pragma unroll
      for (int i = 0; i < 8; ++i) {
        float va = (i < 4) ? f4get(a0, i) : f4get(a1, i - 4);
        float vb = (i < 4) ? f4get(b0, i) : f4get(b1, i - 4);
        int r = i*TT + t;
        unsigned byte = ((unsigned)r << 8) + (((unsigned)(c2*4)) ^ (((unsigned)(r & 7)) << 4));
        *(unsigned*)((char*)xs + byte) = (unsigned)f2bf(va) | ((unsigned)f2bf(vb) << 16);
      }
    }
  }

  const int w = tid >> 6, lane = tid & 63;
  const int l15 = lane & 15, l4 = lane >> 4;

  // ---- preload G^T A-fragments (wave owns c' rows w*32..w*32+31) ----
  bf16x8 gfr[2][4];
  #pragma unroll
  for (int mt = 0; mt < 2; ++mt)
    #pragma unroll
    for (int kt = 0; kt < 4; ++kt)
      gfr[mt][kt] = *(const bf16x8*)(Gtb + (size_t)((w<<5) + (mt<<4) + l15)*CC + (kt<<5) + (l4<<3));
  bf16x8 wfr[4];
  if (w == 3) {
    #pragma unroll
    for (int kt = 0; kt < 4; ++kt) {
      bf16x8 z = {0,0,0,0,0,0,0,0};
      if (l15 == 0) z = *(const bf16x8*)(w0b + (kt<<5) + (l4<<3));
      wfr[kt] = z;
    }
  }
  __syncthreads();

  // ---- Y^T = G^T @ X^T  (M = c' = 128 split across waves; N = 96 (n,t) cols) ----
  #pragma unroll
  for (int np = 0; np < 2; ++np) {
    f32x4 acc[2][3];
    f32x4 accd[3];
    #pragma unroll
    for (int mt = 0; mt < 2; ++mt)
      #pragma unroll
      for (int nt = 0; nt < 3; ++nt) acc[mt][nt] = (f32x4){0.f,0.f,0.f,0.f};
    #pragma unroll
    for (int nt = 0; nt < 3; ++nt) accd[nt] = (f32x4){0.f,0.f,0.f,0.f};

    #pragma unroll
    for (int kt = 0; kt < 4; ++kt) {
      bf16x8 bfr[3];
      #pragma unroll
      for (int nt = 0; nt < 3; ++nt) {
        int rr = np*48 + nt*16 + l15;
        unsigned byte = ((unsigned)rr << 8) +
                        (((unsigned)((kt<<6) + (l4<<4))) ^ (((unsigned)(rr & 7)) << 4));
        bfr[nt] = *(const bf16x8*)((const char*)xs + byte);
      }
      #pragma unroll
      for (int mt = 0; mt < 2; ++mt)
        #pragma unroll
        for (int nt = 0; nt < 3; ++nt)
          acc[mt][nt] = __builtin_amdgcn_mfma_f32_16x16x32_bf16(gfr[mt][kt], bfr[nt], acc[mt][nt], 0, 0, 0);
      if (w == 3) {
        #pragma unroll
        for (int nt = 0; nt < 3; ++nt)
          accd[nt] = __builtin_amdgcn_mfma_f32_16x16x32_bf16(wfr[kt], bfr[nt], accd[nt], 0, 0, 0);
      }
    }
    // write y fragments: lane col=(n,t)=rr, rows c' = w*32+mt*16+l4*4+reg (4 consec) -> b64
    #pragma unroll
    for (int mt = 0; mt < 2; ++mt)
      #pragma unroll
      for (int nt = 0; nt < 3; ++nt) {
        int rr = np*48 + nt*16 + l15;
        ushort4 v;
        v.x = f2bf(acc[mt][nt][0]); v.y = f2bf(acc[mt][nt][1]);
        v.z = f2bf(acc[mt][nt][2]); v.w = f2bf(acc[mt][nt][3]);
        unsigned cb = (unsigned)((w<<6) + (mt<<5) + (l4<<3));
        unsigned byte = ((unsigned)rr << 8) + (cb ^ (((unsigned)(rr & 7)) << 4));
        *(ushort4*)((char*)ys + byte) = v;
      }
    if (w == 3 && l4 == 0) {
      #pragma unroll
      for (int nt = 0; nt < 3; ++nt)
        dsv[np*48 + nt*16 + l15] = accd[nt][0];   // row 0 of the w0-Mt = d
    }
  }
  __syncthreads();

  // ---- per-node scores MFMA + softmax + xw (wave handles nodes 2w, 2w+1) ----
  #pragma unroll
  for (int nn = 0; nn < 2; ++nn) {
    const int n = (w << 1) + nn;
    const int rb = n*TT;
    const int rr = rb + l15;
    f32x4 sa = (f32x4){0.f,0.f,0.f,0.f};
    #pragma unroll
    for (int kt = 0; kt < 4; ++kt) {
      unsigned byte = ((unsigned)rr << 8) +
                      (((unsigned)((kt<<6) + (l4<<4))) ^ (((unsigned)(rr & 7)) << 4));
      bf16x8 afr = *(const bf16x8*)((const char*)ys + byte);  // y rows t
      bf16x8 bfr = *(const bf16x8*)((const char*)xs + byte);  // x rows s (as B)
      sa = __builtin_amdgcn_mfma_f32_16x16x32_bf16(afr, bfr, sa, 0, 0, 0);
    }
    // S[t = l4*4+reg][s = l15]; add d[s], scale, softmax over s (row-wise)
    float dv = dsv[rr];
    const bool sval = (l15 < TT);
    float p[4];
    #pragma unroll
    for (int r = 0; r < 4; ++r) {
      float t1 = sval ? (sa[r] + dv) * RSQRTC : -1e30f;
      float m = t1;
      m = fmaxf(m, __shfl_xor(m, 1));
      m = fmaxf(m, __shfl_xor(m, 2));
      m = fmaxf(m, __shfl_xor(m, 4));
      m = fmaxf(m, __shfl_xor(m, 8));
      float e = exp2f((t1 - m) * 1.4426950408889634f);
      float s = e;
      s += __shfl_xor(s, 1);
      s += __shfl_xor(s, 2);
      s += __shfl_xor(s, 4);
      s += __shfl_xor(s, 8);
      p[r] = e / s;
    }
    // w[s] = sum_t P[t][s]; rows t=12..15 live entirely in l4==3 -> mask
    float wpart = (l4 < 3) ? (p[0] + p[1] + p[2] + p[3]) : 0.f;
    wpart += __shfl_xor(wpart, 16);
    wpart += __shfl_xor(wpart, 32);
    // xw[c] = sum_s w[s] x[n,s,c]; lane owns c = 2*lane, 2*lane+1
    float xw0 = 0.f, xw1 = 0.f;
    #pragma unroll
    for (int s = 0; s < TT; ++s) {
      float wv = __shfl(wpart, s);       // lane s holds w[s]
      int r2 = rb + s;
      unsigned byte = ((unsigned)r2 << 8) +
                      (((unsigned)(lane << 2)) ^ (((unsigned)(r2 & 7)) << 4));
      unsigned xp = *(const unsigned*)((const char*)xs + byte);
      xw0 = fmaf(wv, bfbits2f(xp & 0xffffu), xw0);
      xw1 = fmaf(wv, bfbits2f(xp >> 16), xw1);
    }
    unsafeAtomicAdd(&xwm[(size_t)(n0 + n)*CC + (lane << 1)],     xw0 * 0.125f);
    unsafeAtomicAdd(&xwm[(size_t)(n0 + n)*CC + (lane << 1) + 1], xw1 * 0.125f);
  }
}

// ---------------- K2: P = xwm@Wc1 + b1c, Q = xwm@Wc2 (bf16 out) ----------------------
__global__ __launch_bounds__(256) void k_pq(const float* __restrict__ xwm,
    const float* __restrict__ Wc1, const float* __restrict__ Wc2,
    const float* __restrict__ b1c,
    unsigned short* __restrict__ Pb, unsigned short* __restrict__ Qb) {
  __shared__ float em[4][CC];
  const int tid = threadIdx.x;
  const int n0 = blockIdx.x << 2;
  for (int i = tid; i < 4*CC; i += 256)
    em[i >> 7][i & 127] = xwm[(size_t)(n0 + (i >> 7))*CC + (i & 127)];
  __syncthreads();
  for (int nn = 0; nn < 4; ++nn) {
    for (int half = 0; half < 2; ++half) {
      int f = half*256 + tid;
      float ap = b1c[f], aq = 0.f;
      for (int c = 0; c < CC; ++c) {
        float e = em[nn][c];
        ap = fmaf(e, Wc1[(size_t)c*F1 + f], ap);
        aq = fmaf(e, Wc2[(size_t)c*F1 + f], aq);
      }
      Pb[(size_t)(n0+nn)*F1 + f] = f2bf(ap);
      Qb[(size_t)(n0+nn)*F1 + f] = f2bf(aq);
    }
  }
}

// ---------------- K3: masked stats of z1 = P[row]+Q[col] (batched uint4 gathers) -----
__global__ __launch_bounds__(256) void k_stats1(const unsigned short* __restrict__ Pb,
    const unsigned short* __restrict__ Qb, const int* __restrict__ row,
    const int* __restrict__ col,
    float* __restrict__ sum1, float* __restrict__ sq1, int* __restrict__ icnt) {
  __shared__ int rS[EB], cS[EB]; __shared__ float mk[EB];
  __shared__ float sred[F1], qred[F1];
  const int tid = threadIdx.x;
  const int e0 = blockIdx.x * EB;
  if (tid < EB) {
    int r = row[e0+tid], c = col[e0+tid];
    rS[tid] = r; cS[tid] = c; mk[tid] = (r != c) ? 1.f : 0.f;
  }
  sred[tid] = 0.f; sred[tid+256] = 0.f;
  qred[tid] = 0.f; qred[tid+256] = 0.f;
  __syncthreads();
  if (tid == 0) {
    int lc = 0;
    for (int j = 0; j < EB; ++j) lc += (rS[j] != cS[j]);
    atomicAdd(icnt, lc);
  }
  const int fg = (tid & 63) << 3;   // 8 features per thread
  const int jg = (tid >> 6) << 4;   // wave's first edge
  float s[8], q[8];
  #pragma unroll
  for (int u = 0; u < 8; ++u) { s[u] = 0.f; q[u] = 0.f; }
  #pragma unroll
  for (int i0 = 0; i0 < 16; i0 += 4) {
    // prefetch 4 edges' indices, then issue all 8 gathers back-to-back
    int rr[4], cc[4]; float mm[4];
    #pragma unroll
    for (int u = 0; u < 4; ++u) {
      int j = jg + i0 + u;
      rr[u] = rS[j]; cc[u] = cS[j]; mm[u] = mk[j];
    }
    uint4 pv[4], qv[4];
    #pragma unroll
    for (int u = 0; u < 4; ++u) pv[u] = *(const uint4*)(Pb + (size_t)rr[u]*F1 + fg);
    #pragma unroll
    for (int u = 0; u < 4; ++u) qv[u] = *(const uint4*)(Qb + (size_t)cc[u]*F1 + fg);
    #pragma unroll
    for (int u = 0; u < 4; ++u) {
      float m = mm[u];
      #pragma unroll
      for (int k = 0; k < 4; ++k) {
        unsigned pu = (&pv[u].x)[k], qu = (&qv[u].x)[k];
        float za = bfbits2f(pu & 0xffffu) + bfbits2f(qu & 0xffffu);
        float zb = bfbits2f(pu >> 16)     + bfbits2f(qu >> 16);
        s[2*k]   = fmaf(m, za, s[2*k]);   q[2*k]   = fmaf(m*za, za, q[2*k]);
        s[2*k+1] = fmaf(m, zb, s[2*k+1]); q[2*k+1] = fmaf(m*zb, zb, q[2*k+1]);
      }
    }
  }
  #pragma unroll
  for (int u = 0; u < 8; ++u) {
    atomicAdd(&sred[fg+u], s[u]);
    atomicAdd(&qred[fg+u], q[u]);
  }
  __syncthreads();
  unsafeAtomicAdd(&sum1[tid],     sred[tid]);
  unsafeAtomicAdd(&sum1[tid+256], sred[tid+256]);
  unsafeAtomicAdd(&sq1[tid],      qred[tid]);
  unsafeAtomicAdd(&sq1[tid+256],  qred[tid+256]);
}

__global__ void k_fin1(const float* __restrict__ sum1, const float* __restrict__ sq1,
                       const int* __restrict__ icnt, float* __restrict__ m1,
                       float* __restrict__ is1) {
  int f = threadIdx.x;
  float cnt = (float)(*icnt);
  float m = sum1[f] / cnt;
  m1[f] = m;
  is1[f] = rsqrtf(sq1[f]/cnt - m*m + EPS);
}

// ---------------- K4: h1 = relu(IN(z1)) -> bf16 LDS (swizzled); z2 = h1@W2 via MFMA --
// EBG=32 edges/block, ~38 KB LDS -> 4 blocks/CU; W2T loaded in-loop (L2-resident),
// NO register preload (round-6 spill lesson: preload + launch_bounds(256,4) = scratch).
__global__ __launch_bounds__(256, 4) void k_gemm(const unsigned short* __restrict__ Pb,
    const unsigned short* __restrict__ Qb, const int* __restrict__ row,
    const int* __restrict__ col,
    const float* __restrict__ m1, const float* __restrict__ is1,
    const unsigned short* __restrict__ W2T, const float* __restrict__ b2,
    unsigned short* __restrict__ z2, float* __restrict__ part) {
  __shared__ unsigned short h1s[EBG*F1];  // 32 KB, XOR-swizzled rows; reused as f32 staging
  __shared__ float m1s[F1], is1s[F1];
  __shared__ int rS[EBG], cS[EBG]; __shared__ float mk[EBG];
  __shared__ float cstat[256];
  const int tid = threadIdx.x;
  const int bid = blockIdx.x;
  const int e0 = bid * EBG;
  const int w = tid >> 6, lane = tid & 63;
  const int wn0 = w << 5;
  const int l15 = lane & 15, l4 = lane >> 4;
  if (tid < EBG) {
    int r = row[e0+tid], c = col[e0+tid];
    rS[tid] = r; cS[tid] = c; mk[tid] = (r != c) ? 1.f : 0.f;
  }
  cstat[tid] = 0.f;
  for (int i = tid; i < F1; i += 256) { m1s[i] = m1[i]; is1s[i] = is1[i]; }
  __syncthreads();

  // ---- stage h1 (bf16, swizzled): row j = tid>>3, 8 chunks of 16B; 4-batched loads --
  {
    const int j = tid >> 3;
    const unsigned short* pr = Pb + (size_t)rS[j]*F1;
    const unsigned short* qr = Qb + (size_t)cS[j]*F1;
    const int sw = (j & 7) << 4;
    const unsigned rowb = (unsigned)j << 10;
    const float* m1p = &m1s[0];
    const float* is1p = &is1s[0];
    #pragma unroll
    for (int half = 0; half < 2; ++half) {
      uint4 pv[4], qv[4];
      #pragma unroll
      for (int u = 0; u < 4; ++u) {
        int k0 = (((tid & 7) + ((half*4 + u) << 3)) << 3);
        pv[u] = *(const uint4*)(pr + k0);
        qv[u] = *(const uint4*)(qr + k0);
      }
      #pragma unroll
      for (int u = 0; u < 4; ++u) {
        int k0 = (((tid & 7) + ((half*4 + u) << 3)) << 3);
        unsigned out[4];
        #pragma unroll
        for (int q = 0; q < 4; ++q) {
          unsigned pu = (&pv[u].x)[q], qu = (&qv[u].x)[q];
          int k = k0 + 2*q;
          float2 mm = *(const float2*)&m1p[k];
          float2 ii = *(const float2*)&is1p[k];
          float za = bfbits2f(pu & 0xffffu) + bfbits2f(qu & 0xffffu);
          float zb = bfbits2f(pu >> 16)     + bfbits2f(qu >> 16);
          float ha = fmaxf((za - mm.x)*ii.x, 0.f);
          float hb = fmaxf((zb - mm.y)*ii.y, 0.f);
          out[q] = (unsigned)f2bf(ha) | ((unsigned)f2bf(hb) << 16);
        }
        unsigned byte = rowb + (((unsigned)(k0 << 1)) ^ sw);
        *(uint4*)((char*)h1s + byte) = make_uint4(out[0], out[1], out[2], out[3]);
      }
    }
  }
  __syncthreads();

  // ---- MFMA: 32x128 = [32xK] @ W2T^T, K=512; bfr loaded in-loop (L2 hits) ----
  f32x4 acc[2][2];
  #pragma unroll
  for (int a = 0; a < 2; ++a)
    #pragma unroll
    for (int c = 0; c < 2; ++c) acc[a][c] = (f32x4){0.f,0.f,0.f,0.f};

  const unsigned short* w2p0 = W2T + (size_t)(wn0 + l15)*F1 + (l4 << 3);
  const unsigned short* w2p1 = W2T + (size_t)(wn0 + 16 + l15)*F1 + (l4 << 3);
  #pragma unroll
  for (int kt = 0; kt < 16; ++kt) {
    bf16x8 bfr0 = *(const bf16x8*)(w2p0 + (kt << 5));
    bf16x8 bfr1 = *(const bf16x8*)(w2p1 + (kt << 5));
    bf16x8 afr[2];
    #pragma unroll
    for (int mt = 0; mt < 2; ++mt) {
      int j = (mt << 4) + l15;
      unsigned byte = ((unsigned)j << 10) + (((unsigned)(kt*64 + l4*16)) ^ ((j & 7) << 4));
      afr[mt] = *(const bf16x8*)((const char*)h1s + byte);
    }
    acc[0][0] = __builtin_amdgcn_mfma_f32_16x16x32_bf16(afr[0], bfr0, acc[0][0], 0, 0, 0);
    acc[1][0] = __builtin_amdgcn_mfma_f32_16x16x32_bf16(afr[1], bfr0, acc[1][0], 0, 0, 0);
    acc[0][1] = __builtin_amdgcn_mfma_f32_16x16x32_bf16(afr[0], bfr1, acc[0][1], 0, 0, 0);
    acc[1][1] = __builtin_amdgcn_mfma_f32_16x16x32_bf16(afr[1], bfr1, acc[1][1], 0, 0, 0);
  }
  __syncthreads();   // all h1s reads done; safe to reuse as f32 staging

  // ---- epilogue: +b2, masked col stats, z -> LDS f32 [32][132] ----
  float* z2s = (float*)&h1s[0];
  float sloc[2] = {0.f, 0.f}, qloc[2] = {0.f, 0.f};
  #pragma unroll
  for (int nt = 0; nt < 2; ++nt) {
    int colg = wn0 + (nt << 4) + l15;
    float bb = b2[colg];
    #pragma unroll
    for (int mt = 0; mt < 2; ++mt) {
      f32x4 v = acc[mt][nt];
      #pragma unroll
      for (int reg = 0; reg < 4; ++reg) {
        int j = (mt << 4) + (l4 << 2) + reg;
        float z = v[reg] + bb;
        float m = mk[j];
        sloc[nt] = fmaf(m, z, sloc[nt]);
        qloc[nt] = fmaf(m*z, z, qloc[nt]);
        z2s[j*132 + colg] = z;
      }
    }
  }
  #pragma unroll
  for (int nt = 0; nt < 2; ++nt) {
    int colg = wn0 + (nt << 4) + l15;
    atomicAdd(&cstat[colg], sloc[nt]);
    atomicAdd(&cstat[128 + colg], qloc[nt]);
  }
  __syncthreads();

  // ---- coalesced bf16 z2 store: 2 passes x (256 threads x 8 floats) ----
  #pragma unroll
  for (int p = 0; p < 2; ++p) {
    int idx = (p << 11) + (tid << 3);       // [0, 4096)
    int j = idx >> 7, c = idx & 127;
    const float* src = &z2s[j*132 + c];
    float4 v0 = *(const float4*)src;
    float4 v1 = *(const float4*)(src + 4);
    uint4 o;
    o.x = (unsigned)f2bf(v0.x) | ((unsigned)f2bf(v0.y) << 16);
    o.y = (unsigned)f2bf(v0.z) | ((unsigned)f2bf(v0.w) << 16);
    o.z = (unsigned)f2bf(v1.x) | ((unsigned)f2bf(v1.y) << 16);
    o.w = (unsigned)f2bf(v1.z) | ((unsigned)f2bf(v1.w) << 16);
    *(uint4*)(z2 + (size_t)e0*CC + idx) = o;
  }
  if (tid < 128) {
    part[(size_t)tid*NBLKG2 + bid]         = cstat[tid];
    part[(size_t)(128 + tid)*NBLKG2 + bid] = cstat[128 + tid];
  }
}

__global__ __launch_bounds__(256) void k_fin2(const float* __restrict__ part,
    const int* __restrict__ icnt, float* __restrict__ m2, float* __restrict__ is2) {
  __shared__ float rs[256], rq[256];
  const int c = blockIdx.x, tid = threadIdx.x;
  float s = 0.f, q = 0.f;
  for (int i = tid; i < NBLKG2; i += 256) {
    s += part[(size_t)c*NBLKG2 + i];
    q += part[(size_t)(128 + c)*NBLKG2 + i];
  }
  rs[tid] = s; rq[tid] = q; __syncthreads();
  for (int st = 128; st > 0; st >>= 1) {
    if (tid < st) { rs[tid] += rs[tid+st]; rq[tid] += rq[tid+st]; }
    __syncthreads();
  }
  if (tid == 0) {
    float cnt = (float)(*icnt);
    float m = rs[0] / cnt;
    m2[c] = m;
    is2[c] = rsqrtf(rq[0]/cnt - m*m + EPS);
  }
}

// ---------------- K5a: logits -> att (no table; att is a function of (r,c)) ---------
__global__ __launch_bounds__(256) void k_score(const unsigned short* __restrict__ z2,
    const int* __restrict__ row, const int* __restrict__ col,
    const float* __restrict__ m2, const float* __restrict__ is2,
    const float* __restrict__ W3, const float* __restrict__ b3,
    float* __restrict__ all_att) {
  __shared__ float zt[64][129];
  const int tid = threadIdx.x;
  const int e0 = blockIdx.x << 6;
  const uint4* src = reinterpret_cast<const uint4*>(z2 + (size_t)e0*CC);
  for (int i = tid; i < 64*CC/8; i += 256) {
    uint4 v = src[i];
    int flat = i*8;
    int j = flat >> 7, k = flat & 127;
    zt[j][k+0] = bfbits2f(v.x & 0xffffu); zt[j][k+1] = bfbits2f(v.x >> 16);
    zt[j][k+2] = bfbits2f(v.y & 0xffffu); zt[j][k+3] = bfbits2f(v.y >> 16);
    zt[j][k+4] = bfbits2f(v.z & 0xffffu); zt[j][k+5] = bfbits2f(v.z >> 16);
    zt[j][k+6] = bfbits2f(v.w & 0xffffu); zt[j][k+7] = bfbits2f(v.w >> 16);
  }
  __syncthreads();
  const int j = tid >> 2, q = tid & 3;
  float a = 0.f;
  for (int k = q*32; k < q*32 + 32; ++k)
    a = fmaf(fmaxf((zt[j][k] - m2[k])*is2[k], 0.f), W3[k], a);
  a += __shfl_xor(a, 1, 4);
  a += __shfl_xor(a, 2, 4);
  if (q == 0) {
    int e = e0 + j;
    int r = row[e], c = col[e];
    float att;
    if (r == c) att = 1.f;
    else        att = 1.f / (1.f + expf(-(a + b3[0])));
    all_att[e] = att;
  }
}

// ---------------- K5b: out = 0.5*(att + att[analytic reverse partner]) ---------------
__global__ __launch_bounds__(256) void k_out(const float* __restrict__ all_att,
    float* __restrict__ out) {
  int e = blockIdx.x*256 + threadIdx.x;
  int p = (e < EHALF) ? (e + EHALF) : (e < 2*EHALF ? e - EHALF : e);
  out[e] = 0.5f * (all_att[e] + all_att[p]);
}

extern "C" void kernel_launch(void* const* d_in, const int* in_sizes, int n_in,
                              void* d_out, int out_size, void* d_ws, size_t ws_size,
                              hipStream_t stream) {
  const float* h_in = (const float*)d_in[0];
  const int*   ei   = (const int*)d_in[1];
  const float* Wq = (const float*)d_in[2];
  const float* bq = (const float*)d_in[3];
  const float* Wk = (const float*)d_in[4];
  const float* bk = (const float*)d_in[5];  (void)bk;
  const float* Wv = (const float*)d_in[6];
  const float* bv = (const float*)d_in[7];
  const float* W1 = (const float*)d_in[8];
  const float* b1 = (const float*)d_in[9];
  const float* W2 = (const float*)d_in[10];
  const float* b2 = (const float*)d_in[11];
  const float* W3 = (const float*)d_in[12];
  const float* b3 = (const float*)d_in[13];
  float* ws = (float*)d_ws;
  float* out = (float*)d_out;
  const int* row = ei;
  const int* col = ei + NE;

  // zero accumulators (xwm, sum1, sq1, icnt)
  hipMemsetAsync(ws, 0, 525440ull * 4ull, stream);

  k_pre<<<128, 128, 0, stream>>>(Wq, bq, Wk,
                                 (unsigned short*)(ws+O_GTB), (unsigned short*)(ws+O_W0B));
  k_prew<<<128, 256, 0, stream>>>(Wv, bv, W1, b1, ws+O_WC1, ws+O_WC2, ws+O_B1C);
  k_w2t<<<128, 256, 0, stream>>>(W2, (unsigned short*)(ws+O_W2T));
  k_attn<<<4096, 256, 0, stream>>>(h_in, (const unsigned short*)(ws+O_GTB),
                                   (const unsigned short*)(ws+O_W0B), ws+O_XWM);
  k_pq<<<1024, 256, 0, stream>>>(ws+O_XWM, ws+O_WC1, ws+O_WC2, ws+O_B1C,
                                 (unsigned short*)(ws+O_PB), (unsigned short*)(ws+O_QB));
  k_stats1<<<NBLKG, 256, 0, stream>>>((const unsigned short*)(ws+O_PB),
                                      (const unsigned short*)(ws+O_QB), row, col,
                                      ws+O_SUM1, ws+O_SQ1, (int*)(ws+O_ICNT));
  k_fin1<<<1, 512, 0, stream>>>(ws+O_SUM1, ws+O_SQ1, (const int*)(ws+O_ICNT),
                                ws+O_M1, ws+O_IS1);
  k_gemm<<<NBLKG2, 256, 0, stream>>>((const unsigned short*)(ws+O_PB),
                                     (const unsigned short*)(ws+O_QB), row, col,
                                     ws+O_M1, ws+O_IS1,
                                     (const unsigned short*)(ws+O_W2T), b2,
                                     (unsigned short*)(ws+O_Z2), ws+O_PART);
  k_fin2<<<128, 256, 0, stream>>>(ws+O_PART, (const int*)(ws+O_ICNT), ws+O_M2, ws+O_IS2);
  k_score<<<4160, 256, 0, stream>>>((const unsigned short*)(ws+O_Z2), row, col,
                                    ws+O_M2, ws+O_IS2, W3, b3, ws+O_ALLA);
  k_out<<<1040, 256, 0, stream>>>(ws+O_ALLA, out);
}

// Round 8
// 534.079 us; speedup vs baseline: 1.1797x; 1.1156x over previous
//
#include <hip/hip_runtime.h>
#include <hip/hip_bf16.h>

// Problem constants
#define CC     128        // C
#define TT     12         // T
#define NNODE  4096       // N
#define NE     266240     // E = 2*131072 + 4096
#define EHALF  131072
#define F1     512        // 4C
#define EPS    1e-5f
#define RSQRTC 0.08838834764831845f  // 1/sqrt(128)
#define EB     64         // edges per block (stats + gemm)
#define NBLKG  4160       // NE/EB
#define NF2A   65         // fin2a blocks (4160/64)

// -------- workspace layout (float offsets) --------
#define O_XWM   0ull        // 524288 (zeroed)  xw_mean[N][C]
#define O_SUM1  524288ull   // 512    (zeroed)
#define O_SQ1   524800ull   // 512    (zeroed)
#define O_ICNT  525312ull   // 128    (zeroed; int at [0])
#define O_GTB   525440ull   // bf16[128*128] -> 8192 float slots  (G^T)
#define O_W0B   533632ull   // bf16[128] -> 64
#define O_WC1   533696ull   // 65536   Wv@W1a
#define O_WC2   599232ull   // 65536   Wv@W1b
#define O_B1C   664768ull   // 512
#define O_M1    665280ull   // 512
#define O_IS1   665792ull   // 512
#define O_M2    666304ull   // 128
#define O_IS2   666432ull   // 128
#define O_W2T   666560ull   // bf16[128*512] -> 32768
#define O_PB    699328ull   // bf16[4096*512] -> 1048576
#define O_QB    1747904ull  // 1048576
#define O_ALLA  2796480ull  // 266240
#define O_PART  3062720ull  // 4160*256 = 1064960 (coalesced [bid][stat])
#define O_PART2 4127680ull  // 65*256 = 16640
#define O_Z2    4144320ull  // bf16[NE*128] -> 17039360
// end = 21,183,680 floats ≈ 84.7 MB

typedef __attribute__((ext_vector_type(8))) short bf16x8;
typedef __attribute__((ext_vector_type(4))) float f32x4;

__device__ inline float bfbits2f(unsigned int v) { return __uint_as_float(v << 16); }
__device__ inline unsigned short f2bf(float x) {
  union { __hip_bfloat16 h; unsigned short u; } cv;
  cv.h = __float2bfloat16(x);
  return cv.u;
}
__device__ inline float f4get(const float4& v, int k) {
  return k == 0 ? v.x : k == 1 ? v.y : k == 2 ? v.z : v.w;
}

// ---------------- K0: Gtb = (Wq Wk^T)^T bf16; w0b = bf16(Wk bq) ----------------------
__global__ void k_pre(const float* __restrict__ Wq, const float* __restrict__ bq,
                      const float* __restrict__ Wk,
                      unsigned short* __restrict__ Gtb, unsigned short* __restrict__ w0b) {
  int i = blockIdx.x, j = threadIdx.x;   // G[i][j] = sum_c Wq[i][c] Wk[j][c]
  float acc = 0.f;
  for (int co = 0; co < CC; ++co) acc = fmaf(Wq[i*CC+co], Wk[j*CC+co], acc);
  Gtb[j*CC + i] = f2bf(acc);             // transposed store: Gtb[c'][c] = G[c][c']
  if (j == 0) {
    float a = 0.f;
    for (int co = 0; co < CC; ++co) a = fmaf(Wk[i*CC+co], bq[co], a);
    w0b[i] = f2bf(a);
  }
}

// ---------------- K0b: Wc1 = Wv@W1a, Wc2 = Wv@W1b, b1c = b1 + 12 bv@(W1a+W1b) --------
__global__ __launch_bounds__(256) void k_prew(const float* __restrict__ Wv,
    const float* __restrict__ bv, const float* __restrict__ W1, const float* __restrict__ b1,
    float* __restrict__ Wc1, float* __restrict__ Wc2, float* __restrict__ b1c) {
  __shared__ float wvr[CC];
  const int c = blockIdx.x, tid = threadIdx.x;
  if (tid < CC) wvr[tid] = Wv[(size_t)c*CC + tid];
  __syncthreads();
  for (int h = 0; h < 2; ++h) {
    int f = h*256 + tid;
    float a1 = 0.f, a2 = 0.f;
    for (int j = 0; j < CC; ++j) {
      float wv = wvr[j];
      a1 = fmaf(wv, W1[(size_t)j*F1 + f], a1);
      a2 = fmaf(wv, W1[(size_t)(CC + j)*F1 + f], a2);
    }
    Wc1[(size_t)c*F1 + f] = a1;
    Wc2[(size_t)c*F1 + f] = a2;
  }
  if (c == 0) {
    for (int h = 0; h < 2; ++h) {
      int f = h*256 + tid;
      float s = b1[f];
      for (int j = 0; j < CC; ++j)
        s = fmaf(12.f*bv[j], W1[(size_t)j*F1 + f] + W1[(size_t)(CC + j)*F1 + f], s);
      b1c[f] = s;
    }
  }
}

// ---------------- K0c: W2T bf16 [128 n][512 k] = bf16(W2[k][n]) ----------------------
__global__ void k_w2t(const float* __restrict__ W2, unsigned short* __restrict__ W2T) {
  int n = blockIdx.x;
  for (int k = threadIdx.x; k < F1; k += 256)
    W2T[(size_t)n*F1 + k] = f2bf(W2[(size_t)k*CC + n]);
}

// ---------------- K1: temporal attention -> xw_mean[N][C] (MFMA) ---------------------
// block = 8 nodes of one batch b; 4 waves. XCD-chunked swizzle: XCD k owns batch k.
__global__ __launch_bounds__(256) void k_attn(
    const float* __restrict__ h_in,
    const unsigned short* __restrict__ Gtb,
    const unsigned short* __restrict__ w0b,
    float* __restrict__ xwm) {
  __shared__ unsigned short xs[12800];  // 100 rows x 128 bf16 (256B rows, XOR swizzled)
  __shared__ unsigned short ys[12800];
  __shared__ float dsv[104];            // d[(n,t)] = x . w0
  const int tid = threadIdx.x;
  const int bid = ((blockIdx.x & 7) << 9) | (blockIdx.x >> 3);  // bijective, 4096%8==0
  const int b  = bid >> 9;
  const int n0 = (bid & 511) << 3;

  // ---- load x tile [8 n][12 t][128 c] -> xs bf16, row = n_loc*12+t, swizzled ----
  {
    const float* hb = h_in + ((size_t)b*CC*TT)*NNODE + n0;
    #pragma unroll
    for (int it = 0; it < 3; ++it) {
      int p = it*256 + tid;          // [0,768): c-pair x t
      int c2 = p & 63;               // c = 2*c2, 2*c2+1
      int t  = p >> 6;               // 0..11
      const float* g0 = hb + ((size_t)(2*c2)*TT + t)*NNODE;
      const float* g1 = g0 + (size_t)(TT*NNODE);
      float4 a0 = *(const float4*)g0;
      float4 a1 = *(const float4*)(g0 + 4);
      float4 b0 = *(const float4*)g1;
      float4 b1 = *(const float4*)(g1 + 4);
      #pragma unroll
      for (int i = 0; i < 8; ++i) {
        float va = (i < 4) ? f4get(a0, i) : f4get(a1, i - 4);
        float vb = (i < 4) ? f4get(b0, i) : f4get(b1, i - 4);
        int r = i*TT + t;
        unsigned byte = ((unsigned)r << 8) + (((unsigned)(c2*4)) ^ (((unsigned)(r & 7)) << 4));
        *(unsigned*)((char*)xs + byte) = (unsigned)f2bf(va) | ((unsigned)f2bf(vb) << 16);
      }
    }
  }

  const int w = tid >> 6, lane = tid & 63;
  const int l15 = lane & 15, l4 = lane >> 4;

  // ---- preload G^T A-fragments (wave owns c' rows w*32..w*32+31) ----
  bf16x8 gfr[2][4];
  #pragma unroll
  for (int mt = 0; mt < 2; ++mt)
    #pragma unroll
    for (int kt = 0; kt < 4; ++kt)
      gfr[mt][kt] = *(const bf16x8*)(Gtb + (size_t)((w<<5) + (mt<<4) + l15)*CC + (kt<<5) + (l4<<3));
  bf16x8 wfr[4];
  if (w == 3) {
    #pragma unroll
    for (int kt = 0; kt < 4; ++kt) {
      bf16x8 z = {0,0,0,0,0,0,0,0};
      if (l15 == 0) z = *(const bf16x8*)(w0b + (kt<<5) + (l4<<3));
      wfr[kt] = z;
    }
  }
  __syncthreads();

  // ---- Y^T = G^T @ X^T  (M = c' = 128 split across waves; N = 96 (n,t) cols) ----
  #pragma unroll
  for (int np = 0; np < 2; ++np) {
    f32x4 acc[2][3];
    f32x4 accd[3];
    #pragma unroll
    for (int mt = 0; mt < 2; ++mt)
      #pragma unroll
      for (int nt = 0; nt < 3; ++nt) acc[mt][nt] = (f32x4){0.f,0.f,0.f,0.f};
    #pragma unroll
    for (int nt = 0; nt < 3; ++nt) accd[nt] = (f32x4){0.f,0.f,0.f,0.f};

    #pragma unroll
    for (int kt = 0; kt < 4; ++kt) {
      bf16x8 bfr[3];
      #pragma unroll
      for (int nt = 0; nt < 3; ++nt) {
        int rr = np*48 + nt*16 + l15;
        unsigned byte = ((unsigned)rr << 8) +
                        (((unsigned)((kt<<6) + (l4<<4))) ^ (((unsigned)(rr & 7)) << 4));
        bfr[nt] = *(const bf16x8*)((const char*)xs + byte);
      }
      #pragma unroll
      for (int mt = 0; mt < 2; ++mt)
        #pragma unroll
        for (int nt = 0; nt < 3; ++nt)
          acc[mt][nt] = __builtin_amdgcn_mfma_f32_16x16x32_bf16(gfr[mt][kt], bfr[nt], acc[mt][nt], 0, 0, 0);
      if (w == 3) {
        #pragma unroll
        for (int nt = 0; nt < 3; ++nt)
          accd[nt] = __builtin_amdgcn_mfma_f32_16x16x32_bf16(wfr[kt], bfr[nt], accd[nt], 0, 0, 0);
      }
    }
    // write y fragments: lane col=(n,t)=rr, rows c' = w*32+mt*16+l4*4+reg (4 consec) -> b64
    #pragma unroll
    for (int mt = 0; mt < 2; ++mt)
      #pragma unroll
      for (int nt = 0; nt < 3; ++nt) {
        int rr = np*48 + nt*16 + l15;
        ushort4 v;
        v.x = f2bf(acc[mt][nt][0]); v.y = f2bf(acc[mt][nt][1]);
        v.z = f2bf(acc[mt][nt][2]); v.w = f2bf(acc[mt][nt][3]);
        unsigned cb = (unsigned)((w<<6) + (mt<<5) + (l4<<3));
        unsigned byte = ((unsigned)rr << 8) + (cb ^ (((unsigned)(rr & 7)) << 4));
        *(ushort4*)((char*)ys + byte) = v;
      }
    if (w == 3 && l4 == 0) {
      #pragma unroll
      for (int nt = 0; nt < 3; ++nt)
        dsv[np*48 + nt*16 + l15] = accd[nt][0];   // row 0 of the w0-Mt = d
    }
  }
  __syncthreads();

  // ---- per-node scores MFMA + softmax + xw (wave handles nodes 2w, 2w+1) ----
  #pragma unroll
  for (int nn = 0; nn < 2; ++nn) {
    const int n = (w << 1) + nn;
    const int rb = n*TT;
    const int rr = rb + l15;
    f32x4 sa = (f32x4){0.f,0.f,0.f,0.f};
    #pragma unroll
    for (int kt = 0; kt < 4; ++kt) {
      unsigned byte = ((unsigned)rr << 8) +
                      (((unsigned)((kt<<6) + (l4<<4))) ^ (((unsigned)(rr & 7)) << 4));
      bf16x8 afr = *(const bf16x8*)((const char*)ys + byte);  // y rows t
      bf16x8 bfr = *(const bf16x8*)((const char*)xs + byte);  // x rows s (as B)
      sa = __builtin_amdgcn_mfma_f32_16x16x32_bf16(afr, bfr, sa, 0, 0, 0);
    }
    // S[t = l4*4+reg][s = l15]; add d[s], scale, softmax over s (row-wise)
    float dv = dsv[rr];
    const bool sval = (l15 < TT);
    float p[4];
    #pragma unroll
    for (int r = 0; r < 4; ++r) {
      float t1 = sval ? (sa[r] + dv) * RSQRTC : -1e30f;
      float m = t1;
      m = fmaxf(m, __shfl_xor(m, 1));
      m = fmaxf(m, __shfl_xor(m, 2));
      m = fmaxf(m, __shfl_xor(m, 4));
      m = fmaxf(m, __shfl_xor(m, 8));
      float e = exp2f((t1 - m) * 1.4426950408889634f);
      float s = e;
      s += __shfl_xor(s, 1);
      s += __shfl_xor(s, 2);
      s += __shfl_xor(s, 4);
      s += __shfl_xor(s, 8);
      p[r] = e / s;
    }
    // w[s] = sum_t P[t][s]; rows t=12..15 live entirely in l4==3 -> mask
    float wpart = (l4 < 3) ? (p[0] + p[1] + p[2] + p[3]) : 0.f;
    wpart += __shfl_xor(wpart, 16);
    wpart += __shfl_xor(wpart, 32);
    // xw[c] = sum_s w[s] x[n,s,c]; lane owns c = 2*lane, 2*lane+1
    float xw0 = 0.f, xw1 = 0.f;
    #pragma unroll
    for (int s = 0; s < TT; ++s) {
      float wv = __shfl(wpart, s);       // lane s holds w[s]
      int r2 = rb + s;
      unsigned byte = ((unsigned)r2 << 8) +
                      (((unsigned)(lane << 2)) ^ (((unsigned)(r2 & 7)) << 4));
      unsigned xp = *(const unsigned*)((const char*)xs + byte);
      xw0 = fmaf(wv, bfbits2f(xp & 0xffffu), xw0);
      xw1 = fmaf(wv, bfbits2f(xp >> 16), xw1);
    }
    unsafeAtomicAdd(&xwm[(size_t)(n0 + n)*CC + (lane << 1)],     xw0 * 0.125f);
    unsafeAtomicAdd(&xwm[(size_t)(n0 + n)*CC + (lane << 1) + 1], xw1 * 0.125f);
  }
}

// ---------------- K2: P = xwm@Wc1 + b1c, Q = xwm@Wc2 (bf16 out) ----------------------
__global__ __launch_bounds__(256) void k_pq(const float* __restrict__ xwm,
    const float* __restrict__ Wc1, const float* __restrict__ Wc2,
    const float* __restrict__ b1c,
    unsigned short* __restrict__ Pb, unsigned short* __restrict__ Qb) {
  __shared__ float em[4][CC];
  const int tid = threadIdx.x;
  const int n0 = blockIdx.x << 2;
  for (int i = tid; i < 4*CC; i += 256)
    em[i >> 7][i & 127] = xwm[(size_t)(n0 + (i >> 7))*CC + (i & 127)];
  __syncthreads();
  for (int nn = 0; nn < 4; ++nn) {
    for (int half = 0; half < 2; ++half) {
      int f = half*256 + tid;
      float ap = b1c[f], aq = 0.f;
      for (int c = 0; c < CC; ++c) {
        float e = em[nn][c];
        ap = fmaf(e, Wc1[(size_t)c*F1 + f], ap);
        aq = fmaf(e, Wc2[(size_t)c*F1 + f], aq);
      }
      Pb[(size_t)(n0+nn)*F1 + f] = f2bf(ap);
      Qb[(size_t)(n0+nn)*F1 + f] = f2bf(aq);
    }
  }
}

// ---------------- K3: masked stats of z1 = P[row]+Q[col] (batched uint4 gathers) -----
__global__ __launch_bounds__(256) void k_stats1(const unsigned short* __restrict__ Pb,
    const unsigned short* __restrict__ Qb, const int* __restrict__ row,
    const int* __restrict__ col,
    float* __restrict__ sum1, float* __restrict__ sq1, int* __restrict__ icnt) {
  __shared__ int rS[EB], cS[EB]; __shared__ float mk[EB];
  __shared__ float sred[F1], qred[F1];
  const int tid = threadIdx.x;
  const int e0 = blockIdx.x * EB;
  if (tid < EB) {
    int r = row[e0+tid], c = col[e0+tid];
    rS[tid] = r; cS[tid] = c; mk[tid] = (r != c) ? 1.f : 0.f;
  }
  sred[tid] = 0.f; sred[tid+256] = 0.f;
  qred[tid] = 0.f; qred[tid+256] = 0.f;
  __syncthreads();
  if (tid == 0) {
    int lc = 0;
    for (int j = 0; j < EB; ++j) lc += (rS[j] != cS[j]);
    atomicAdd(icnt, lc);
  }
  const int fg = (tid & 63) << 3;   // 8 features per thread
  const int jg = (tid >> 6) << 4;   // wave's first edge
  float s[8], q[8];
  #pragma unroll
  for (int u = 0; u < 8; ++u) { s[u] = 0.f; q[u] = 0.f; }
  #pragma unroll
  for (int i0 = 0; i0 < 16; i0 += 4) {
    // prefetch 4 edges' indices, then issue all 8 gathers back-to-back
    int rr[4], cc[4]; float mm[4];
    #pragma unroll
    for (int u = 0; u < 4; ++u) {
      int j = jg + i0 + u;
      rr[u] = rS[j]; cc[u] = cS[j]; mm[u] = mk[j];
    }
    uint4 pv[4], qv[4];
    #pragma unroll
    for (int u = 0; u < 4; ++u) pv[u] = *(const uint4*)(Pb + (size_t)rr[u]*F1 + fg);
    #pragma unroll
    for (int u = 0; u < 4; ++u) qv[u] = *(const uint4*)(Qb + (size_t)cc[u]*F1 + fg);
    #pragma unroll
    for (int u = 0; u < 4; ++u) {
      float m = mm[u];
      #pragma unroll
      for (int k = 0; k < 4; ++k) {
        unsigned pu = (&pv[u].x)[k], qu = (&qv[u].x)[k];
        float za = bfbits2f(pu & 0xffffu) + bfbits2f(qu & 0xffffu);
        float zb = bfbits2f(pu >> 16)     + bfbits2f(qu >> 16);
        s[2*k]   = fmaf(m, za, s[2*k]);   q[2*k]   = fmaf(m*za, za, q[2*k]);
        s[2*k+1] = fmaf(m, zb, s[2*k+1]); q[2*k+1] = fmaf(m*zb, zb, q[2*k+1]);
      }
    }
  }
  #pragma unroll
  for (int u = 0; u < 8; ++u) {
    atomicAdd(&sred[fg+u], s[u]);
    atomicAdd(&qred[fg+u], q[u]);
  }
  __syncthreads();
  unsafeAtomicAdd(&sum1[tid],     sred[tid]);
  unsafeAtomicAdd(&sum1[tid+256], sred[tid+256]);
  unsafeAtomicAdd(&sq1[tid],      qred[tid]);
  unsafeAtomicAdd(&sq1[tid+256],  qred[tid+256]);
}

__global__ void k_fin1(const float* __restrict__ sum1, const float* __restrict__ sq1,
                       const int* __restrict__ icnt, float* __restrict__ m1,
                       float* __restrict__ is1) {
  int f = threadIdx.x;
  float cnt = (float)(*icnt);
  float m = sum1[f] / cnt;
  m1[f] = m;
  is1[f] = rsqrtf(sq1[f]/cnt - m*m + EPS);
}

// ---------------- K4: h1 = relu(IN(z1)) -> bf16 LDS (swizzled); z2 = h1@W2 via MFMA --
// EB=64, 512 threads (8 waves): 2 blocks/CU (LDS ~70KB) = 16 waves/CU. Each wave owns
// 16 output cols (acc = 16 VGPR). W2T loaded in-loop (L2-resident). part coalesced.
__global__ __launch_bounds__(512, 4) void k_gemm(const unsigned short* __restrict__ Pb,
    const unsigned short* __restrict__ Qb, const int* __restrict__ row,
    const int* __restrict__ col,
    const float* __restrict__ m1, const float* __restrict__ is1,
    const unsigned short* __restrict__ W2T, const float* __restrict__ b2,
    unsigned short* __restrict__ z2, float* __restrict__ part) {
  __shared__ unsigned short h1s[EB*F1];   // 64 KB, XOR-swizzled rows; reused as f32 staging
  __shared__ float m1s[F1], is1s[F1];
  __shared__ int rS[EB], cS[EB]; __shared__ float mk[EB];
  __shared__ float cstat[256];
  const int tid = threadIdx.x;
  const int bid = blockIdx.x;
  const int e0 = bid * EB;
  const int w = tid >> 6, lane = tid & 63;
  const int wn0 = w << 4;               // wave owns cols wn0..wn0+15
  const int l15 = lane & 15, l4 = lane >> 4;
  if (tid < EB) {
    int r = row[e0+tid], c = col[e0+tid];
    rS[tid] = r; cS[tid] = c; mk[tid] = (r != c) ? 1.f : 0.f;
  }
  for (int i = tid; i < F1; i += 512) { m1s[i] = m1[i]; is1s[i] = is1[i]; }
  __syncthreads();

  // ---- stage h1 (bf16, swizzled): row j = tid>>3; 8 threads/row, 8 chunks each ----
  {
    const int j = tid >> 3;
    const unsigned short* pr = Pb + (size_t)rS[j]*F1;
    const unsigned short* qr = Qb + (size_t)cS[j]*F1;
    const int sw = (j & 7) << 4;
    const unsigned rowb = (unsigned)j << 10;
    #pragma unroll
    for (int half = 0; half < 2; ++half) {
      uint4 pv[4], qv[4];
      #pragma unroll
      for (int u = 0; u < 4; ++u) {
        int k0 = (((tid & 7) + ((half*4 + u) << 3)) << 3);
        pv[u] = *(const uint4*)(pr + k0);
        qv[u] = *(const uint4*)(qr + k0);
      }
      #pragma unroll
      for (int u = 0; u < 4; ++u) {
        int k0 = (((tid & 7) + ((half*4 + u) << 3)) << 3);
        unsigned out[4];
        #pragma unroll
        for (int q = 0; q < 4; ++q) {
          unsigned pu = (&pv[u].x)[q], qu = (&qv[u].x)[q];
          int k = k0 + 2*q;
          float2 mm = *(const float2*)&m1s[k];
          float2 ii = *(const float2*)&is1s[k];
          float za = bfbits2f(pu & 0xffffu) + bfbits2f(qu & 0xffffu);
          float zb = bfbits2f(pu >> 16)     + bfbits2f(qu >> 16);
          float ha = fmaxf((za - mm.x)*ii.x, 0.f);
          float hb = fmaxf((zb - mm.y)*ii.y, 0.f);
          out[q] = (unsigned)f2bf(ha) | ((unsigned)f2bf(hb) << 16);
        }
        unsigned byte = rowb + (((unsigned)(k0 << 1)) ^ sw);
        *(uint4*)((char*)h1s + byte) = make_uint4(out[0], out[1], out[2], out[3]);
      }
    }
  }
  __syncthreads();

  // ---- MFMA: 64x16 per wave = [64xK] @ W2T[wn0..wn0+15]^T, K=512 ----
  f32x4 acc[4];
  #pragma unroll
  for (int a = 0; a < 4; ++a) acc[a] = (f32x4){0.f,0.f,0.f,0.f};

  const unsigned short* w2p = W2T + (size_t)(wn0 + l15)*F1 + (l4 << 3);
  #pragma unroll
  for (int kt = 0; kt < 16; ++kt) {
    bf16x8 bfr = *(const bf16x8*)(w2p + (kt << 5));
    bf16x8 afr[4];
    #pragma unroll
    for (int mt = 0; mt < 4; ++mt) {
      int j = (mt << 4) + l15;
      unsigned byte = ((unsigned)j << 10) + (((unsigned)(kt*64 + l4*16)) ^ ((j & 7) << 4));
      afr[mt] = *(const bf16x8*)((const char*)h1s + byte);
    }
    #pragma unroll
    for (int mt = 0; mt < 4; ++mt)
      acc[mt] = __builtin_amdgcn_mfma_f32_16x16x32_bf16(afr[mt], bfr, acc[mt], 0, 0, 0);
  }
  __syncthreads();   // all h1s reads done; safe to reuse as f32 staging

  // ---- epilogue: +b2, masked col stats, z -> LDS f32 [64][132] ----
  float* z2s = (float*)&h1s[0];
  const int colg = wn0 + l15;
  {
    float bb = b2[colg];
    float sloc = 0.f, qloc = 0.f;
    #pragma unroll
    for (int mt = 0; mt < 4; ++mt) {
      f32x4 v = acc[mt];
      #pragma unroll
      for (int reg = 0; reg < 4; ++reg) {
        int j = (mt << 4) + (l4 << 2) + reg;
        float z = v[reg] + bb;
        float m = mk[j];
        sloc = fmaf(m, z, sloc);
        qloc = fmaf(m*z, z, qloc);
        z2s[j*132 + colg] = z;
      }
    }
    // reduce across l4 groups (lanes sharing colg) then lane group 0 stores
    sloc += __shfl_xor(sloc, 16); sloc += __shfl_xor(sloc, 32);
    qloc += __shfl_xor(qloc, 16); qloc += __shfl_xor(qloc, 32);
    if (l4 == 0) { cstat[colg] = sloc; cstat[128 + colg] = qloc; }
  }
  __syncthreads();

  // ---- coalesced bf16 z2 store: 2 passes x (512 threads x 8 floats) ----
  #pragma unroll
  for (int p = 0; p < 2; ++p) {
    int idx = (p << 12) + (tid << 3);       // [0, 8192)
    int j = idx >> 7, c = idx & 127;
    const float* src = &z2s[j*132 + c];
    float4 v0 = *(const float4*)src;
    float4 v1 = *(const float4*)(src + 4);
    uint4 o;
    o.x = (unsigned)f2bf(v0.x) | ((unsigned)f2bf(v0.y) << 16);
    o.y = (unsigned)f2bf(v0.z) | ((unsigned)f2bf(v0.w) << 16);
    o.z = (unsigned)f2bf(v1.x) | ((unsigned)f2bf(v1.y) << 16);
    o.w = (unsigned)f2bf(v1.z) | ((unsigned)f2bf(v1.w) << 16);
    *(uint4*)(z2 + (size_t)e0*CC + idx) = o;
  }
  if (tid < 256) part[(size_t)bid*256 + tid] = cstat[tid];   // coalesced 1KB/block
}

// ---------------- K4b: partial reduce of part [4160][256] -> part2 [65][256] --------
__global__ __launch_bounds__(256) void k_fin2a(const float* __restrict__ part,
                                               float* __restrict__ part2) {
  const int g = blockIdx.x, tid = threadIdx.x;
  float s = 0.f;
  #pragma unroll 4
  for (int r = 0; r < 64; ++r)
    s += part[(size_t)(g*64 + r)*256 + tid];
  part2[(size_t)g*256 + tid] = s;
}

__global__ __launch_bounds__(256) void k_fin2b(const float* __restrict__ part2,
    const int* __restrict__ icnt, float* __restrict__ m2, float* __restrict__ is2) {
  __shared__ float red[256];
  const int tid = threadIdx.x;
  float s = 0.f;
  for (int g = 0; g < NF2A; ++g) s += part2[(size_t)g*256 + tid];
  red[tid] = s;
  __syncthreads();
  if (tid < 128) {
    float cnt = (float)(*icnt);
    float m = red[tid] / cnt;
    m2[tid] = m;
    is2[tid] = rsqrtf(red[128 + tid]/cnt - m*m + EPS);
  }
}

// ---------------- K5a: logits -> att (no table; att is a function of (r,c)) ---------
__global__ __launch_bounds__(256) void k_score(const unsigned short* __restrict__ z2,
    const int* __restrict__ row, const int* __restrict__ col,
    const float* __restrict__ m2, const float* __restrict__ is2,
    const float* __restrict__ W3, const float* __restrict__ b3,
    float* __restrict__ all_att) {
  __shared__ float zt[64][129];
  const int tid = threadIdx.x;
  const int e0 = blockIdx.x << 6;
  const uint4* src = reinterpret_cast<const uint4*>(z2 + (size_t)e0*CC);
  for (int i = tid; i < 64*CC/8; i += 256) {
    uint4 v = src[i];
    int flat = i*8;
    int j = flat >> 7, k = flat & 127;
    zt[j][k+0] = bfbits2f(v.x & 0xffffu); zt[j][k+1] = bfbits2f(v.x >> 16);
    zt[j][k+2] = bfbits2f(v.y & 0xffffu); zt[j][k+3] = bfbits2f(v.y >> 16);
    zt[j][k+4] = bfbits2f(v.z & 0xffffu); zt[j][k+5] = bfbits2f(v.z >> 16);
    zt[j][k+6] = bfbits2f(v.w & 0xffffu); zt[j][k+7] = bfbits2f(v.w >> 16);
  }
  __syncthreads();
  const int j = tid >> 2, q = tid & 3;
  float a = 0.f;
  for (int k = q*32; k < q*32 + 32; ++k)
    a = fmaf(fmaxf((zt[j][k] - m2[k])*is2[k], 0.f), W3[k], a);
  a += __shfl_xor(a, 1, 4);
  a += __shfl_xor(a, 2, 4);
  if (q == 0) {
    int e = e0 + j;
    int r = row[e], c = col[e];
    float att;
    if (r == c) att = 1.f;
    else        att = 1.f / (1.f + expf(-(a + b3[0])));
    all_att[e] = att;
  }
}

// ---------------- K5b: out = 0.5*(att + att[analytic reverse partner]) ---------------
__global__ __launch_bounds__(256) void k_out(const float* __restrict__ all_att,
    float* __restrict__ out) {
  int e = blockIdx.x*256 + threadIdx.x;
  int p = (e < EHALF) ? (e + EHALF) : (e < 2*EHALF ? e - EHALF : e);
  out[e] = 0.5f * (all_att[e] + all_att[p]);
}

extern "C" void kernel_launch(void* const* d_in, const int* in_sizes, int n_in,
                              void* d_out, int out_size, void* d_ws, size_t ws_size,
                              hipStream_t stream) {
  const float* h_in = (const float*)d_in[0];
  const int*   ei   = (const int*)d_in[1];
  const float* Wq = (const float*)d_in[2];
  const float* bq = (const float*)d_in[3];
  const float* Wk = (const float*)d_in[4];
  const float* bk = (const float*)d_in[5];  (void)bk;
  const float* Wv = (const float*)d_in[6];
  const float* bv = (const float*)d_in[7];
  const float* W1 = (const float*)d_in[8];
  const float* b1 = (const float*)d_in[9];
  const float* W2 = (const float*)d_in[10];
  const float* b2 = (const float*)d_in[11];
  const float* W3 = (const float*)d_in[12];
  const float* b3 = (const float*)d_in[13];
  float* ws = (float*)d_ws;
  float* out = (float*)d_out;
  const int* row = ei;
  const int* col = ei + NE;

  // zero accumulators (xwm, sum1, sq1, icnt)
  hipMemsetAsync(ws, 0, 525440ull * 4ull, stream);

  k_pre<<<128, 128, 0, stream>>>(Wq, bq, Wk,
                                 (unsigned short*)(ws+O_GTB), (unsigned short*)(ws+O_W0B));
  k_prew<<<128, 256, 0, stream>>>(Wv, bv, W1, b1, ws+O_WC1, ws+O_WC2, ws+O_B1C);
  k_w2t<<<128, 256, 0, stream>>>(W2, (unsigned short*)(ws+O_W2T));
  k_attn<<<4096, 256, 0, stream>>>(h_in, (const unsigned short*)(ws+O_GTB),
                                   (const unsigned short*)(ws+O_W0B), ws+O_XWM);
  k_pq<<<1024, 256, 0, stream>>>(ws+O_XWM, ws+O_WC1, ws+O_WC2, ws+O_B1C,
                                 (unsigned short*)(ws+O_PB), (unsigned short*)(ws+O_QB));
  k_stats1<<<NBLKG, 256, 0, stream>>>((const unsigned short*)(ws+O_PB),
                                      (const unsigned short*)(ws+O_QB), row, col,
                                      ws+O_SUM1, ws+O_SQ1, (int*)(ws+O_ICNT));
  k_fin1<<<1, 512, 0, stream>>>(ws+O_SUM1, ws+O_SQ1, (const int*)(ws+O_ICNT),
                                ws+O_M1, ws+O_IS1);
  k_gemm<<<NBLKG, 512, 0, stream>>>((const unsigned short*)(ws+O_PB),
                                    (const unsigned short*)(ws+O_QB), row, col,
                                    ws+O_M1, ws+O_IS1,
                                    (const unsigned short*)(ws+O_W2T), b2,
                                    (unsigned short*)(ws+O_Z2), ws+O_PART);
  k_fin2a<<<NF2A, 256, 0, stream>>>(ws+O_PART, ws+O_PART2);
  k_fin2b<<<1, 256, 0, stream>>>(ws+O_PART2, (const int*)(ws+O_ICNT), ws+O_M2, ws+O_IS2);
  k_score<<<4160, 256, 0, stream>>>((const unsigned short*)(ws+O_Z2), row, col,
                                    ws+O_M2, ws+O_IS2, W3, b3, ws+O_ALLA);
  k_out<<<1040, 256, 0, stream>>>(ws+O_ALLA, out);
}

// Round 9
// 496.402 us; speedup vs baseline: 1.2693x; 1.0759x over previous
//
#include <hip/hip_runtime.h>
#include <hip/hip_bf16.h>

// Problem constants
#define CC     128        // C
#define TT     12         // T
#define NNODE  4096       // N
#define NE     266240     // E = 2*131072 + 4096
#define EHALF  131072
#define F1     512        // 4C
#define EPS    1e-5f
#define RSQRTC 0.08838834764831845f  // 1/sqrt(128)
#define EB     64         // edges per block (gemm)
#define NBLKG  4160       // NE/EB
#define NF2A   65         // fin2a blocks
#define ST     40         // k_S LDS row stride (shorts): 80B rows, 16B-aligned frags

// -------- workspace layout (float offsets) --------
// zeroed prefix [0, 546048):
#define O_XWM   0ull        // 524288  xw_mean[N][C]
#define O_W1S   524288ull   // 512     w1 = sum1
#define O_W2S   524800ull   // 512     w2 = node quad part
#define O_ICNT  525312ull   // 128     int icnt at [0]
#define O_CNT   525440ull   // 4096    int cnt[n]
#define O_T     529536ull   // 128     t[b]
#define O_S     529664ull   // 16384   S[a][b]
// not zeroed:
#define O_GTB   546048ull   // 8192
#define O_W0B   554240ull   // 64
#define O_WC1   554304ull   // 65536
#define O_WC2   619840ull   // 65536
#define O_B1C   685376ull   // 512
#define O_M1    685888ull   // 512
#define O_IS1   686400ull   // 512
#define O_M2    686912ull   // 128
#define O_IS2   687040ull   // 128
#define O_CROSS 687168ull   // 512
#define O_W2T   687680ull   // 32768
#define O_PB    720448ull   // 1048576
#define O_QB    1769024ull  // 1048576
#define O_ALLA  2817600ull  // 266240
#define O_PART  3083840ull  // 1064960
#define O_PART2 4148800ull  // 16640
#define O_Z2    4165440ull  // 17039360
// end = 21,204,800 floats ≈ 84.8 MB

typedef __attribute__((ext_vector_type(8))) short bf16x8;
typedef __attribute__((ext_vector_type(4))) float f32x4;

__device__ inline float bfbits2f(unsigned int v) { return __uint_as_float(v << 16); }
__device__ inline unsigned short f2bf(float x) {
  union { __hip_bfloat16 h; unsigned short u; } cv;
  cv.h = __float2bfloat16(x);
  return cv.u;
}
__device__ inline float f4get(const float4& v, int k) {
  return k == 0 ? v.x : k == 1 ? v.y : k == 2 ? v.z : v.w;
}

// ---------------- K0: Gtb = (Wq Wk^T)^T bf16; w0b = bf16(Wk bq) ----------------------
__global__ void k_pre(const float* __restrict__ Wq, const float* __restrict__ bq,
                      const float* __restrict__ Wk,
                      unsigned short* __restrict__ Gtb, unsigned short* __restrict__ w0b) {
  int i = blockIdx.x, j = threadIdx.x;
  float acc = 0.f;
  for (int co = 0; co < CC; ++co) acc = fmaf(Wq[i*CC+co], Wk[j*CC+co], acc);
  Gtb[j*CC + i] = f2bf(acc);
  if (j == 0) {
    float a = 0.f;
    for (int co = 0; co < CC; ++co) a = fmaf(Wk[i*CC+co], bq[co], a);
    w0b[i] = f2bf(a);
  }
}

// ---------------- K0b: Wc1 = Wv@W1a, Wc2 = Wv@W1b, b1c = b1 + 12 bv@(W1a+W1b) --------
__global__ __launch_bounds__(256) void k_prew(const float* __restrict__ Wv,
    const float* __restrict__ bv, const float* __restrict__ W1, const float* __restrict__ b1,
    float* __restrict__ Wc1, float* __restrict__ Wc2, float* __restrict__ b1c) {
  __shared__ float wvr[CC];
  const int c = blockIdx.x, tid = threadIdx.x;
  if (tid < CC) wvr[tid] = Wv[(size_t)c*CC + tid];
  __syncthreads();
  for (int h = 0; h < 2; ++h) {
    int f = h*256 + tid;
    float a1 = 0.f, a2 = 0.f;
    for (int j = 0; j < CC; ++j) {
      float wv = wvr[j];
      a1 = fmaf(wv, W1[(size_t)j*F1 + f], a1);
      a2 = fmaf(wv, W1[(size_t)(CC + j)*F1 + f], a2);
    }
    Wc1[(size_t)c*F1 + f] = a1;
    Wc2[(size_t)c*F1 + f] = a2;
  }
  if (c == 0) {
    for (int h = 0; h < 2; ++h) {
      int f = h*256 + tid;
      float s = b1[f];
      for (int j = 0; j < CC; ++j)
        s = fmaf(12.f*bv[j], W1[(size_t)j*F1 + f] + W1[(size_t)(CC + j)*F1 + f], s);
      b1c[f] = s;
    }
  }
}

// ---------------- K0c: W2T bf16 [128 n][512 k] ---------------------------------------
__global__ void k_w2t(const float* __restrict__ W2, unsigned short* __restrict__ W2T) {
  int n = blockIdx.x;
  for (int k = threadIdx.x; k < F1; k += 256)
    W2T[(size_t)n*F1 + k] = f2bf(W2[(size_t)k*CC + n]);
}

// ---------------- K0d: cnt[n] histogram + icnt over non-self edges -------------------
__global__ __launch_bounds__(256) void k_hist(const int* __restrict__ row,
    const int* __restrict__ col, int* __restrict__ cnt, int* __restrict__ icnt) {
  __shared__ int h[NNODE];   // 16 KB
  const int tid = threadIdx.x;
  for (int i = tid; i < NNODE; i += 256) h[i] = 0;
  __syncthreads();
  int lc = 0;
  const int base = blockIdx.x << 12;    // 4096 edges/block; grid 64 covers 2*EHALF
  for (int i = tid; i < 4096; i += 256) {
    int e = base + i;
    int r = row[e], c = col[e];
    if (r != c) { atomicAdd(&h[r], 1); ++lc; }
  }
  #pragma unroll
  for (int d = 1; d < 64; d <<= 1) lc += __shfl_xor(lc, d);
  __syncthreads();
  for (int i = tid; i < NNODE; i += 256) { int v = h[i]; if (v) atomicAdd(&cnt[i], v); }
  if ((tid & 63) == 0) atomicAdd(icnt, lc);
}

// ---------------- K1: temporal attention -> xw_mean[N][C] (MFMA) ---------------------
__global__ __launch_bounds__(256) void k_attn(
    const float* __restrict__ h_in,
    const unsigned short* __restrict__ Gtb,
    const unsigned short* __restrict__ w0b,
    float* __restrict__ xwm) {
  __shared__ unsigned short xs[12800];
  __shared__ unsigned short ys[12800];
  __shared__ float dsv[104];
  const int tid = threadIdx.x;
  const int bid = ((blockIdx.x & 7) << 9) | (blockIdx.x >> 3);
  const int b  = bid >> 9;
  const int n0 = (bid & 511) << 3;

  {
    const float* hb = h_in + ((size_t)b*CC*TT)*NNODE + n0;
    #pragma unroll
    for (int it = 0; it < 3; ++it) {
      int p = it*256 + tid;
      int c2 = p & 63;
      int t  = p >> 6;
      const float* g0 = hb + ((size_t)(2*c2)*TT + t)*NNODE;
      const float* g1 = g0 + (size_t)(TT*NNODE);
      float4 a0 = *(const float4*)g0;
      float4 a1 = *(const float4*)(g0 + 4);
      float4 b0 = *(const float4*)g1;
      float4 b1 = *(const float4*)(g1 + 4);
      #pragma unroll
      for (int i = 0; i < 8; ++i) {
        float va = (i < 4) ? f4get(a0, i) : f4get(a1, i - 4);
        float vb = (i < 4) ? f4get(b0, i) : f4get(b1, i - 4);
        int r = i*TT + t;
        unsigned byte = ((unsigned)r << 8) + (((unsigned)(c2*4)) ^ (((unsigned)(r & 7)) << 4));
        *(unsigned*)((char*)xs + byte) = (unsigned)f2bf(va) | ((unsigned)f2bf(vb) << 16);
      }
    }
  }

  const int w = tid >> 6, lane = tid & 63;
  const int l15 = lane & 15, l4 = lane >> 4;

  bf16x8 gfr[2][4];
  #pragma unroll
  for (int mt = 0; mt < 2; ++mt)
    #pragma unroll
    for (int kt = 0; kt < 4; ++kt)
      gfr[mt][kt] = *(const bf16x8*)(Gtb + (size_t)((w<<5) + (mt<<4) + l15)*CC + (kt<<5) + (l4<<3));
  bf16x8 wfr[4];
  if (w == 3) {
    #pragma unroll
    for (int kt = 0; kt < 4; ++kt) {
      bf16x8 z = {0,0,0,0,0,0,0,0};
      if (l15 == 0) z = *(const bf16x8*)(w0b + (kt<<5) + (l4<<3));
      wfr[kt] = z;
    }
  }
  __syncthreads();

  #pragma unroll
  for (int np = 0; np < 2; ++np) {
    f32x4 acc[2][3];
    f32x4 accd[3];
    #pragma unroll
    for (int mt = 0; mt < 2; ++mt)
      #pragma unroll
      for (int nt = 0; nt < 3; ++nt) acc[mt][nt] = (f32x4){0.f,0.f,0.f,0.f};
    #pragma unroll
    for (int nt = 0; nt < 3; ++nt) accd[nt] = (f32x4){0.f,0.f,0.f,0.f};

    #pragma unroll
    for (int kt = 0; kt < 4; ++kt) {
      bf16x8 bfr[3];
      #pragma unroll
      for (int nt = 0; nt < 3; ++nt) {
        int rr = np*48 + nt*16 + l15;
        unsigned byte = ((unsigned)rr << 8) +
                        (((unsigned)((kt<<6) + (l4<<4))) ^ (((unsigned)(rr & 7)) << 4));
        bfr[nt] = *(const bf16x8*)((const char*)xs + byte);
      }
      #pragma unroll
      for (int mt = 0; mt < 2; ++mt)
        #pragma unroll
        for (int nt = 0; nt < 3; ++nt)
          acc[mt][nt] = __builtin_amdgcn_mfma_f32_16x16x32_bf16(gfr[mt][kt], bfr[nt], acc[mt][nt], 0, 0, 0);
      if (w == 3) {
        #pragma unroll
        for (int nt = 0; nt < 3; ++nt)
          accd[nt] = __builtin_amdgcn_mfma_f32_16x16x32_bf16(wfr[kt], bfr[nt], accd[nt], 0, 0, 0);
      }
    }
    #pragma unroll
    for (int mt = 0; mt < 2; ++mt)
      #pragma unroll
      for (int nt = 0; nt < 3; ++nt) {
        int rr = np*48 + nt*16 + l15;
        ushort4 v;
        v.x = f2bf(acc[mt][nt][0]); v.y = f2bf(acc[mt][nt][1]);
        v.z = f2bf(acc[mt][nt][2]); v.w = f2bf(acc[mt][nt][3]);
        unsigned cb = (unsigned)((w<<6) + (mt<<5) + (l4<<3));
        unsigned byte = ((unsigned)rr << 8) + (cb ^ (((unsigned)(rr & 7)) << 4));
        *(ushort4*)((char*)ys + byte) = v;
      }
    if (w == 3 && l4 == 0) {
      #pragma unroll
      for (int nt = 0; nt < 3; ++nt)
        dsv[np*48 + nt*16 + l15] = accd[nt][0];
    }
  }
  __syncthreads();

  #pragma unroll
  for (int nn = 0; nn < 2; ++nn) {
    const int n = (w << 1) + nn;
    const int rb = n*TT;
    const int rr = rb + l15;
    f32x4 sa = (f32x4){0.f,0.f,0.f,0.f};
    #pragma unroll
    for (int kt = 0; kt < 4; ++kt) {
      unsigned byte = ((unsigned)rr << 8) +
                      (((unsigned)((kt<<6) + (l4<<4))) ^ (((unsigned)(rr & 7)) << 4));
      bf16x8 afr = *(const bf16x8*)((const char*)ys + byte);
      bf16x8 bfr = *(const bf16x8*)((const char*)xs + byte);
      sa = __builtin_amdgcn_mfma_f32_16x16x32_bf16(afr, bfr, sa, 0, 0, 0);
    }
    float dv = dsv[rr];
    const bool sval = (l15 < TT);
    float p[4];
    #pragma unroll
    for (int r = 0; r < 4; ++r) {
      float t1 = sval ? (sa[r] + dv) * RSQRTC : -1e30f;
      float m = t1;
      m = fmaxf(m, __shfl_xor(m, 1));
      m = fmaxf(m, __shfl_xor(m, 2));
      m = fmaxf(m, __shfl_xor(m, 4));
      m = fmaxf(m, __shfl_xor(m, 8));
      float e = exp2f((t1 - m) * 1.4426950408889634f);
      float s = e;
      s += __shfl_xor(s, 1);
      s += __shfl_xor(s, 2);
      s += __shfl_xor(s, 4);
      s += __shfl_xor(s, 8);
      p[r] = e / s;
    }
    float wpart = (l4 < 3) ? (p[0] + p[1] + p[2] + p[3]) : 0.f;
    wpart += __shfl_xor(wpart, 16);
    wpart += __shfl_xor(wpart, 32);
    float xw0 = 0.f, xw1 = 0.f;
    #pragma unroll
    for (int s = 0; s < TT; ++s) {
      float wv = __shfl(wpart, s);
      int r2 = rb + s;
      unsigned byte = ((unsigned)r2 << 8) +
                      (((unsigned)(lane << 2)) ^ (((unsigned)(r2 & 7)) << 4));
      unsigned xp = *(const unsigned*)((const char*)xs + byte);
      xw0 = fmaf(wv, bfbits2f(xp & 0xffffu), xw0);
      xw1 = fmaf(wv, bfbits2f(xp >> 16), xw1);
    }
    unsafeAtomicAdd(&xwm[(size_t)(n0 + n)*CC + (lane << 1)],     xw0 * 0.125f);
    unsafeAtomicAdd(&xwm[(size_t)(n0 + n)*CC + (lane << 1) + 1], xw1 * 0.125f);
  }
}

// ---------------- K1b: t[b] = sum_n cnt[n] * xwm[n][b] -------------------------------
__global__ __launch_bounds__(256) void k_t(const float* __restrict__ xwm,
    const int* __restrict__ cnt, float* __restrict__ t) {
  __shared__ float ts[256];
  const int tid = threadIdx.x;
  const int f = tid & 127;
  const int n0 = blockIdx.x << 7;
  float s = 0.f;
  for (int i = (tid >> 7); i < 128; i += 2) {
    int n = n0 + i;
    s = fmaf((float)cnt[n], xwm[(size_t)n*CC + f], s);
  }
  ts[tid] = s;
  __syncthreads();
  if (tid < 128) unsafeAtomicAdd(&t[f], ts[tid] + ts[tid + 128]);
}

// ---------------- K1c: S[a][b] += sum_e mask xwm[row,a]*xwm[col,b] via MFMA ----------
// grid 512 x 256thr; block handles 512 edges in 16 batches of 32. xwm is 2MB (L2-hot).
__global__ __launch_bounds__(256) void k_S(const float* __restrict__ xwm,
    const int* __restrict__ row, const int* __restrict__ col, float* __restrict__ S) {
  __shared__ unsigned short XT[128*ST];   // [a][j] bf16, 80B rows
  __shared__ unsigned short YT[128*ST];   // [b][j] bf16 (zeroed row when self-loop)
  const int tid = threadIdx.x;
  const int w = tid >> 6, lane = tid & 63, l15 = lane & 15, l4 = lane >> 4;
  const int j = tid & 31, fi = tid >> 5;   // staging role: edge j, feature block fi
  const int f0 = fi << 4;
  f32x4 acc[2][8];
  #pragma unroll
  for (int mt = 0; mt < 2; ++mt)
    #pragma unroll
    for (int nt = 0; nt < 8; ++nt) acc[mt][nt] = (f32x4){0.f,0.f,0.f,0.f};

  const int ebase = blockIdx.x << 9;   // 512 edges per block (512*512 = 2*EHALF)
  for (int bt = 0; bt < 16; ++bt) {
    const int e = ebase + (bt << 5) + j;
    const int r = row[e], c = col[e];
    const bool msk = (r != c);
    const float* xr = xwm + (size_t)r*CC + f0;
    const float* xc = xwm + (size_t)c*CC + f0;
    float4 xv[4], yv[4];
    #pragma unroll
    for (int u = 0; u < 4; ++u) { xv[u] = *(const float4*)(xr + 4*u); yv[u] = *(const float4*)(xc + 4*u); }
    __syncthreads();   // previous batch's frag reads complete
    #pragma unroll
    for (int u = 0; u < 16; ++u) {
      float xvv = f4get(xv[u >> 2], u & 3);
      float yvv = f4get(yv[u >> 2], u & 3);
      XT[(f0+u)*ST + j] = f2bf(xvv);
      YT[(f0+u)*ST + j] = msk ? f2bf(yvv) : (unsigned short)0;
    }
    __syncthreads();
    bf16x8 af[2];
    #pragma unroll
    for (int mt = 0; mt < 2; ++mt)
      af[mt] = *(const bf16x8*)&XT[((((w<<1)+mt)<<4) + l15)*ST + (l4<<3)];
    #pragma unroll
    for (int nt = 0; nt < 8; ++nt) {
      bf16x8 bf_ = *(const bf16x8*)&YT[(((nt<<4) + l15))*ST + (l4<<3)];
      acc[0][nt] = __builtin_amdgcn_mfma_f32_16x16x32_bf16(af[0], bf_, acc[0][nt], 0, 0, 0);
      acc[1][nt] = __builtin_amdgcn_mfma_f32_16x16x32_bf16(af[1], bf_, acc[1][nt], 0, 0, 0);
    }
  }
  // merge into global S (64 KB, L2-hot)
  #pragma unroll
  for (int mt = 0; mt < 2; ++mt)
    #pragma unroll
    for (int nt = 0; nt < 8; ++nt)
      #pragma unroll
      for (int reg = 0; reg < 4; ++reg) {
        int a = (((w<<1)+mt)<<4) + (l4<<2) + reg;
        int b = (nt<<4) + l15;
        unsafeAtomicAdd(&S[a*128 + b], acc[mt][nt][reg]);
      }
}

// ---------------- K1d: cross[f] = sum_ab Wc1[a,f]Wc2[b,f]S[a,b] + b1c[f]*(t@Wc2)[f] --
__global__ __launch_bounds__(128) void k_cross(const float* __restrict__ S,
    const float* __restrict__ Wc1, const float* __restrict__ Wc2,
    const float* __restrict__ b1c, const float* __restrict__ t,
    float* __restrict__ cross) {
  __shared__ float w2c[128];
  __shared__ float red[128], red2[128];
  const int f = blockIdx.x, a = threadIdx.x;
  w2c[a] = Wc2[(size_t)a*F1 + f];
  __syncthreads();
  float v = 0.f;
  const float* Sr = S + a*128;
  for (int b = 0; b < 128; b += 4) {
    float4 sv = *(const float4*)(Sr + b);
    v = fmaf(sv.x, w2c[b],   v); v = fmaf(sv.y, w2c[b+1], v);
    v = fmaf(sv.z, w2c[b+2], v); v = fmaf(sv.w, w2c[b+3], v);
  }
  float pa = Wc1[(size_t)a*F1 + f] * v;
  float ta = t[a] * w2c[a];
  #pragma unroll
  for (int d = 1; d < 64; d <<= 1) { pa += __shfl_xor(pa, d); ta += __shfl_xor(ta, d); }
  red[a] = pa; red2[a] = ta;
  __syncthreads();
  if (a == 0) cross[f] = red[0] + red[64] + b1c[f]*(red2[0] + red2[64]);
}

// ---------------- K2: P,Q (bf16) + node-weighted stats (w1, w2) ----------------------
__global__ __launch_bounds__(256) void k_pq(const float* __restrict__ xwm,
    const float* __restrict__ Wc1, const float* __restrict__ Wc2,
    const float* __restrict__ b1c, const int* __restrict__ cnt,
    unsigned short* __restrict__ Pb, unsigned short* __restrict__ Qb,
    float* __restrict__ w1, float* __restrict__ w2) {
  __shared__ float em[4][CC];
  const int tid = threadIdx.x;
  const int n0 = blockIdx.x << 2;
  for (int i = tid; i < 4*CC; i += 256)
    em[i >> 7][i & 127] = xwm[(size_t)(n0 + (i >> 7))*CC + (i & 127)];
  __syncthreads();
  float ws[2] = {0.f, 0.f}, qs[2] = {0.f, 0.f};
  for (int nn = 0; nn < 4; ++nn) {
    const float cw = (float)cnt[n0 + nn];
    for (int half = 0; half < 2; ++half) {
      int f = half*256 + tid;
      float ap = b1c[f], aq = 0.f;
      for (int c = 0; c < CC; ++c) {
        float e = em[nn][c];
        ap = fmaf(e, Wc1[(size_t)c*F1 + f], ap);
        aq = fmaf(e, Wc2[(size_t)c*F1 + f], aq);
      }
      unsigned short pu = f2bf(ap), qu = f2bf(aq);
      Pb[(size_t)(n0+nn)*F1 + f] = pu;
      Qb[(size_t)(n0+nn)*F1 + f] = qu;
      float pf = bfbits2f(pu), qf = bfbits2f(qu);
      ws[half] = fmaf(cw, pf + qf, ws[half]);
      qs[half] = fmaf(cw, pf*pf + qf*qf, qs[half]);
    }
  }
  unsafeAtomicAdd(&w1[tid],       ws[0]);
  unsafeAtomicAdd(&w1[tid + 256], ws[1]);
  unsafeAtomicAdd(&w2[tid],       qs[0]);
  unsafeAtomicAdd(&w2[tid + 256], qs[1]);
}

// ---------------- K3: combine stats -------------------------------------------------
__global__ void k_fin1(const float* __restrict__ w1, const float* __restrict__ w2,
                       const float* __restrict__ cross, const int* __restrict__ icnt,
                       float* __restrict__ m1, float* __restrict__ is1) {
  int f = threadIdx.x;
  float cnt = (float)(*icnt);
  float m = w1[f] / cnt;
  m1[f] = m;
  is1[f] = rsqrtf((w2[f] + 2.f*cross[f]) / cnt - m*m + EPS);
}

// ---------------- K4: h1 = relu(IN(z1)) -> bf16 LDS (swizzled); z2 = h1@W2 via MFMA --
__global__ __launch_bounds__(512, 4) void k_gemm(const unsigned short* __restrict__ Pb,
    const unsigned short* __restrict__ Qb, const int* __restrict__ row,
    const int* __restrict__ col,
    const float* __restrict__ m1, const float* __restrict__ is1,
    const unsigned short* __restrict__ W2T, const float* __restrict__ b2,
    unsigned short* __restrict__ z2, float* __restrict__ part) {
  __shared__ unsigned short h1s[EB*F1];
  __shared__ float m1s[F1], is1s[F1];
  __shared__ int rS[EB], cS[EB]; __shared__ float mk[EB];
  __shared__ float cstat[256];
  const int tid = threadIdx.x;
  const int bid = blockIdx.x;
  const int e0 = bid * EB;
  const int w = tid >> 6, lane = tid & 63;
  const int wn0 = w << 4;
  const int l15 = lane & 15, l4 = lane >> 4;
  if (tid < EB) {
    int r = row[e0+tid], c = col[e0+tid];
    rS[tid] = r; cS[tid] = c; mk[tid] = (r != c) ? 1.f : 0.f;
  }
  for (int i = tid; i < F1; i += 512) { m1s[i] = m1[i]; is1s[i] = is1[i]; }
  __syncthreads();

  {
    const int j = tid >> 3;
    const unsigned short* pr = Pb + (size_t)rS[j]*F1;
    const unsigned short* qr = Qb + (size_t)cS[j]*F1;
    const int sw = (j & 7) << 4;
    const unsigned rowb = (unsigned)j << 10;
    #pragma unroll
    for (int half = 0; half < 2; ++half) {
      uint4 pv[4], qv[4];
      #pragma unroll
      for (int u = 0; u < 4; ++u) {
        int k0 = (((tid & 7) + ((half*4 + u) << 3)) << 3);
        pv[u] = *(const uint4*)(pr + k0);
        qv[u] = *(const uint4*)(qr + k0);
      }
      #pragma unroll
      for (int u = 0; u < 4; ++u) {
        int k0 = (((tid & 7) + ((half*4 + u) << 3)) << 3);
        unsigned out[4];
        #pragma unroll
        for (int q = 0; q < 4; ++q) {
          unsigned pu = (&pv[u].x)[q], qu = (&qv[u].x)[q];
          int k = k0 + 2*q;
          float2 mm = *(const float2*)&m1s[k];
          float2 ii = *(const float2*)&is1s[k];
          float za = bfbits2f(pu & 0xffffu) + bfbits2f(qu & 0xffffu);
          float zb = bfbits2f(pu >> 16)     + bfbits2f(qu >> 16);
          float ha = fmaxf((za - mm.x)*ii.x, 0.f);
          float hb = fmaxf((zb - mm.y)*ii.y, 0.f);
          out[q] = (unsigned)f2bf(ha) | ((unsigned)f2bf(hb) << 16);
        }
        unsigned byte = rowb + (((unsigned)(k0 << 1)) ^ sw);
        *(uint4*)((char*)h1s + byte) = make_uint4(out[0], out[1], out[2], out[3]);
      }
    }
  }
  __syncthreads();

  f32x4 acc[4];
  #pragma unroll
  for (int a = 0; a < 4; ++a) acc[a] = (f32x4){0.f,0.f,0.f,0.f};

  const unsigned short* w2p = W2T + (size_t)(wn0 + l15)*F1 + (l4 << 3);
  #pragma unroll
  for (int kt = 0; kt < 16; ++kt) {
    bf16x8 bfr = *(const bf16x8*)(w2p + (kt << 5));
    bf16x8 afr[4];
    #pragma unroll
    for (int mt = 0; mt < 4; ++mt) {
      int j = (mt << 4) + l15;
      unsigned byte = ((unsigned)j << 10) + (((unsigned)(kt*64 + l4*16)) ^ ((j & 7) << 4));
      afr[mt] = *(const bf16x8*)((const char*)h1s + byte);
    }
    #pragma unroll
    for (int mt = 0; mt < 4; ++mt)
      acc[mt] = __builtin_amdgcn_mfma_f32_16x16x32_bf16(afr[mt], bfr, acc[mt], 0, 0, 0);
  }
  __syncthreads();

  float* z2s = (float*)&h1s[0];
  const int colg = wn0 + l15;
  {
    float bb = b2[colg];
    float sloc = 0.f, qloc = 0.f;
    #pragma unroll
    for (int mt = 0; mt < 4; ++mt) {
      f32x4 v = acc[mt];
      #pragma unroll
      for (int reg = 0; reg < 4; ++reg) {
        int j = (mt << 4) + (l4 << 2) + reg;
        float z = v[reg] + bb;
        float m = mk[j];
        sloc = fmaf(m, z, sloc);
        qloc = fmaf(m*z, z, qloc);
        z2s[j*132 + colg] = z;
      }
    }
    sloc += __shfl_xor(sloc, 16); sloc += __shfl_xor(sloc, 32);
    qloc += __shfl_xor(qloc, 16); qloc += __shfl_xor(qloc, 32);
    if (l4 == 0) { cstat[colg] = sloc; cstat[128 + colg] = qloc; }
  }
  __syncthreads();

  #pragma unroll
  for (int p = 0; p < 2; ++p) {
    int idx = (p << 12) + (tid << 3);
    int j = idx >> 7, c = idx & 127;
    const float* src = &z2s[j*132 + c];
    float4 v0 = *(const float4*)src;
    float4 v1 = *(const float4*)(src + 4);
    uint4 o;
    o.x = (unsigned)f2bf(v0.x) | ((unsigned)f2bf(v0.y) << 16);
    o.y = (unsigned)f2bf(v0.z) | ((unsigned)f2bf(v0.w) << 16);
    o.z = (unsigned)f2bf(v1.x) | ((unsigned)f2bf(v1.y) << 16);
    o.w = (unsigned)f2bf(v1.z) | ((unsigned)f2bf(v1.w) << 16);
    *(uint4*)(z2 + (size_t)e0*CC + idx) = o;
  }
  if (tid < 256) part[(size_t)bid*256 + tid] = cstat[tid];
}

// ---------------- K4b/K4c: stat reduction -------------------------------------------
__global__ __launch_bounds__(256) void k_fin2a(const float* __restrict__ part,
                                               float* __restrict__ part2) {
  const int g = blockIdx.x, tid = threadIdx.x;
  float s = 0.f;
  #pragma unroll 4
  for (int r = 0; r < 64; ++r)
    s += part[(size_t)(g*64 + r)*256 + tid];
  part2[(size_t)g*256 + tid] = s;
}

__global__ __launch_bounds__(256) void k_fin2b(const float* __restrict__ part2,
    const int* __restrict__ icnt, float* __restrict__ m2, float* __restrict__ is2) {
  __shared__ float red[256];
  const int tid = threadIdx.x;
  float s = 0.f;
  for (int g = 0; g < NF2A; ++g) s += part2[(size_t)g*256 + tid];
  red[tid] = s;
  __syncthreads();
  if (tid < 128) {
    float cnt = (float)(*icnt);
    float m = red[tid] / cnt;
    m2[tid] = m;
    is2[tid] = rsqrtf(red[128 + tid]/cnt - m*m + EPS);
  }
}

// ---------------- K5a: logits -> att ------------------------------------------------
__global__ __launch_bounds__(256) void k_score(const unsigned short* __restrict__ z2,
    const int* __restrict__ row, const int* __restrict__ col,
    const float* __restrict__ m2, const float* __restrict__ is2,
    const float* __restrict__ W3, const float* __restrict__ b3,
    float* __restrict__ all_att) {
  __shared__ float zt[64][129];
  const int tid = threadIdx.x;
  const int e0 = blockIdx.x << 6;
  const uint4* src = reinterpret_cast<const uint4*>(z2 + (size_t)e0*CC);
  for (int i = tid; i < 64*CC/8; i += 256) {
    uint4 v = src[i];
    int flat = i*8;
    int j = flat >> 7, k = flat & 127;
    zt[j][k+0] = bfbits2f(v.x & 0xffffu); zt[j][k+1] = bfbits2f(v.x >> 16);
    zt[j][k+2] = bfbits2f(v.y & 0xffffu); zt[j][k+3] = bfbits2f(v.y >> 16);
    zt[j][k+4] = bfbits2f(v.z & 0xffffu); zt[j][k+5] = bfbits2f(v.z >> 16);
    zt[j][k+6] = bfbits2f(v.w & 0xffffu); zt[j][k+7] = bfbits2f(v.w >> 16);
  }
  __syncthreads();
  const int j = tid >> 2, q = tid & 3;
  float a = 0.f;
  for (int k = q*32; k < q*32 + 32; ++k)
    a = fmaf(fmaxf((zt[j][k] - m2[k])*is2[k], 0.f), W3[k], a);
  a += __shfl_xor(a, 1, 4);
  a += __shfl_xor(a, 2, 4);
  if (q == 0) {
    int e = e0 + j;
    int r = row[e], c = col[e];
    float att;
    if (r == c) att = 1.f;
    else        att = 1.f / (1.f + expf(-(a + b3[0])));
    all_att[e] = att;
  }
}

// ---------------- K5b: out = 0.5*(att + att[analytic reverse partner]) ---------------
__global__ __launch_bounds__(256) void k_out(const float* __restrict__ all_att,
    float* __restrict__ out) {
  int e = blockIdx.x*256 + threadIdx.x;
  int p = (e < EHALF) ? (e + EHALF) : (e < 2*EHALF ? e - EHALF : e);
  out[e] = 0.5f * (all_att[e] + all_att[p]);
}

extern "C" void kernel_launch(void* const* d_in, const int* in_sizes, int n_in,
                              void* d_out, int out_size, void* d_ws, size_t ws_size,
                              hipStream_t stream) {
  const float* h_in = (const float*)d_in[0];
  const int*   ei   = (const int*)d_in[1];
  const float* Wq = (const float*)d_in[2];
  const float* bq = (const float*)d_in[3];
  const float* Wk = (const float*)d_in[4];
  const float* bk = (const float*)d_in[5];  (void)bk;
  const float* Wv = (const float*)d_in[6];
  const float* bv = (const float*)d_in[7];
  const float* W1 = (const float*)d_in[8];
  const float* b1 = (const float*)d_in[9];
  const float* W2 = (const float*)d_in[10];
  const float* b2 = (const float*)d_in[11];
  const float* W3 = (const float*)d_in[12];
  const float* b3 = (const float*)d_in[13];
  float* ws = (float*)d_ws;
  float* out = (float*)d_out;
  const int* row = ei;
  const int* col = ei + NE;

  // zero accumulators: xwm, w1, w2, icnt, cnt, t, S
  hipMemsetAsync(ws, 0, 546048ull * 4ull, stream);

  k_pre<<<128, 128, 0, stream>>>(Wq, bq, Wk,
                                 (unsigned short*)(ws+O_GTB), (unsigned short*)(ws+O_W0B));
  k_prew<<<128, 256, 0, stream>>>(Wv, bv, W1, b1, ws+O_WC1, ws+O_WC2, ws+O_B1C);
  k_w2t<<<128, 256, 0, stream>>>(W2, (unsigned short*)(ws+O_W2T));
  k_hist<<<64, 256, 0, stream>>>(row, col, (int*)(ws+O_CNT), (int*)(ws+O_ICNT));
  k_attn<<<4096, 256, 0, stream>>>(h_in, (const unsigned short*)(ws+O_GTB),
                                   (const unsigned short*)(ws+O_W0B), ws+O_XWM);
  k_t<<<32, 256, 0, stream>>>(ws+O_XWM, (const int*)(ws+O_CNT), ws+O_T);
  k_S<<<512, 256, 0, stream>>>(ws+O_XWM, row, col, ws+O_S);
  k_pq<<<1024, 256, 0, stream>>>(ws+O_XWM, ws+O_WC1, ws+O_WC2, ws+O_B1C,
                                 (const int*)(ws+O_CNT),
                                 (unsigned short*)(ws+O_PB), (unsigned short*)(ws+O_QB),
                                 ws+O_W1S, ws+O_W2S);
  k_cross<<<512, 128, 0, stream>>>(ws+O_S, ws+O_WC1, ws+O_WC2, ws+O_B1C, ws+O_T,
                                   ws+O_CROSS);
  k_fin1<<<1, 512, 0, stream>>>(ws+O_W1S, ws+O_W2S, ws+O_CROSS,
                                (const int*)(ws+O_ICNT), ws+O_M1, ws+O_IS1);
  k_gemm<<<NBLKG, 512, 0, stream>>>((const unsigned short*)(ws+O_PB),
                                    (const unsigned short*)(ws+O_QB), row, col,
                                    ws+O_M1, ws+O_IS1,
                                    (const unsigned short*)(ws+O_W2T), b2,
                                    (unsigned short*)(ws+O_Z2), ws+O_PART);
  k_fin2a<<<NF2A, 256, 0, stream>>>(ws+O_PART, ws+O_PART2);
  k_fin2b<<<1, 256, 0, stream>>>(ws+O_PART2, (const int*)(ws+O_ICNT), ws+O_M2, ws+O_IS2);
  k_score<<<4160, 256, 0, stream>>>((const unsigned short*)(ws+O_Z2), row, col,
                                    ws+O_M2, ws+O_IS2, W3, b3, ws+O_ALLA);
  k_out<<<1040, 256, 0, stream>>>(ws+O_ALLA, out);
}